// Round 11
// baseline (1326.594 us; speedup 1.0000x reference)
//
#include <hip/hip_runtime.h>
#include <hip/hip_bf16.h>

#define B_ 2048
#define S_ 71
#define D_ 768
#define H_ 4
#define DH_ 192
#define TD_ 2304            // 3*D
#define M_ (B_ * S_)        // 145408 = 1136*128
#define TEXT_ 35
#define NKT 12              // 768 / 64 K-tiles

typedef unsigned short u16;
typedef unsigned int u32;
typedef __attribute__((ext_vector_type(4))) float f32x4;
typedef __attribute__((ext_vector_type(8))) short bf16x8;

__device__ __forceinline__ u16 f2bf(float f) {
  u32 u = __float_as_uint(f);
  u32 r = (u + 0x7FFFu + ((u >> 16) & 1u)) >> 16;  // RNE
  return (u16)r;
}
__device__ __forceinline__ float bf2f(u16 x) {
  return __uint_as_float(((u32)x) << 16);
}
// HW packed fp32->bf16 RNE (2 elems / instruction); no builtin on gfx950
__device__ __forceinline__ u32 pk_bf16(float lo, float hi) {
  u32 r;
  asm("v_cvt_pk_bf16_f32 %0, %1, %2" : "=v"(r) : "v"(lo), "v"(hi));
  return r;
}

typedef __attribute__((address_space(1))) const unsigned int GASU;
typedef __attribute__((address_space(3))) unsigned int LASU;
__device__ __forceinline__ void gload16(const void* g, void* l) {
  __builtin_amdgcn_global_load_lds((GASU*)g, (LASU*)l, 16, 0, 0);
}

#define PHASE_BAR() do { __builtin_amdgcn_s_barrier(); asm volatile("" ::: "memory"); } while (0)
#define LGKM0() do { asm volatile("s_waitcnt lgkmcnt(0)" ::: "memory"); __builtin_amdgcn_sched_barrier(0); } while (0)

// ---------------------------------------------------------------------------
// fp32 -> bf16 elementwise, 8 elems/thread, exact grid (used for w_qkv only)
__global__ __launch_bounds__(256) void k_cvt_bf16(const float* __restrict__ in,
                                                  u16* __restrict__ out, int n8) {
  int idx = blockIdx.x * 256 + threadIdx.x;
  if (idx >= n8) return;
  const float4* p = (const float4*)(in + (size_t)idx * 8);
  float4 a = p[0], b = p[1];
  uint4 o;
  o.x = pk_bf16(a.x, a.y);
  o.y = pk_bf16(a.z, a.w);
  o.z = pk_bf16(b.x, b.y);
  o.w = pk_bf16(b.z, b.w);
  *(uint4*)(out + (size_t)idx * 8) = o;
}

// ---------------------------------------------------------------------------
// w_out [e][d] -> w_outT [d][e]  (768x768 fp32, tiny)
__global__ void k_transpose768(const float* __restrict__ in, float* __restrict__ out) {
  int idx = blockIdx.x * 256 + threadIdx.x;
  int e = idx / 768, d = idx % 768;
  out[(size_t)d * 768 + e] = in[idx];
}

// ---------------------------------------------------------------------------
// GEMM: C[M,2304] = A[M,768](fp32, converted in-kernel) * Bw[2304,768](bf16),
// bias + phi epilogue. 128x256 tile, BK=64, 8 waves 64x64, A dbuf (2x16KB) +
// B single (32KB) = 64KB LDS, launch_bounds(512,4) -> 2 blocks/CU.
// A REG-STAGED fp32->bf16 via v_cvt_pk_bf16_f32 (1 inst / 2 elems; round-10's
// manual RNE bit-math was ~80 VALU ops/thread/tile and pushed VALUBusy to 39%).
__global__ __launch_bounds__(512, 4) void k_gemm_qkv(
    const float* __restrict__ Afp,  // [M_,768] fp32 (features)
    const u16* __restrict__ Bw,     // [2304,768] bf16 (n-major)
    const float* __restrict__ bias, // [2304]
    u16* __restrict__ C)            // [M_,2304] bf16, phi on cols<1536
{
  // u16 units: A0 [0,8192), A1 [8192,16384), B [16384,32768)
  __shared__ u16 sm[32768];   // 64 KiB
  int t = threadIdx.x;
  int lane = t & 63, wid = t >> 6;
  int wr = wid >> 2, wc = wid & 3;     // 2 x 4 wave grid, wave tile 64x64
  int lr = lane & 15;
  int g4 = lane >> 4;

  // XCD-bijective swizzle: nwg = 10224 = 8*1278; bn inner -> A-panel L2 reuse
  int swz = (blockIdx.x & 7) * 1278 + (blockIdx.x >> 3);
  int bm = swz / 9, bn = swz % 9;
  const size_t arow0 = (size_t)bm * 128;
  const int bcol0 = bn * 256;

  // A: 1024 granule-chunks (8 elems), 2/thread. chunk c: row=c>>3, source
  // granule pre-swizzled (c&7)^(row&7); LDS dst linear c*8 (u16).
  const float* srcAf[2];
  int dA[2];
#pragma unroll
  for (int j = 0; j < 2; ++j) {
    int c = j * 512 + t;
    srcAf[j] = Afp + (arow0 + (c >> 3)) * 768 + ((c & 7) ^ ((c >> 3) & 7)) * 8;
    dA[j] = c * 8;
  }
  // B: gload_lds, 2048 chunks, 4/thread (same pre-swizzled source)
  const u16* srcB[4];
  int dB[4];
#pragma unroll
  for (int j = 0; j < 4; ++j) {
    int c = j * 512 + t;
    srcB[j] = Bw + (size_t)(bcol0 + (c >> 3)) * 768 + ((c & 7) ^ ((c >> 3) & 7)) * 8;
    dB[j] = 16384 + c * 8;
  }

#define STAGE_B(ktu) do { \
  gload16(srcB[0] + (ktu), &sm[dB[0]]); \
  gload16(srcB[1] + (ktu), &sm[dB[1]]); \
  gload16(srcB[2] + (ktu), &sm[dB[2]]); \
  gload16(srcB[3] + (ktu), &sm[dB[3]]); \
} while (0)
#define LOADA(ktu) do { \
  fa0 = *(const float4*)(srcAf[0] + (ktu)); \
  fa1 = *(const float4*)(srcAf[0] + (ktu) + 4); \
  fa2 = *(const float4*)(srcAf[1] + (ktu)); \
  fa3 = *(const float4*)(srcAf[1] + (ktu) + 4); \
} while (0)
#define WRITEA(abuf) do { \
  uint4 o0; \
  o0.x = pk_bf16(fa0.x, fa0.y); o0.y = pk_bf16(fa0.z, fa0.w); \
  o0.z = pk_bf16(fa1.x, fa1.y); o0.w = pk_bf16(fa1.z, fa1.w); \
  *(uint4*)(&sm[(abuf) + dA[0]]) = o0; \
  uint4 o1; \
  o1.x = pk_bf16(fa2.x, fa2.y); o1.y = pk_bf16(fa2.z, fa2.w); \
  o1.z = pk_bf16(fa3.x, fa3.y); o1.w = pk_bf16(fa3.z, fa3.w); \
  *(uint4*)(&sm[(abuf) + dA[1]]) = o1; \
} while (0)

  // fragment addresses (swizzled read side)
  int gx0 = g4 ^ (lr & 7);             // kk=0 granule; kk=1 -> gx0^4
  int aro = (wr * 64 + lr) * 64;       // + mi*1024 + gx*8  (u16)
  int bro = 16384 + (wc * 64 + lr) * 64;

  f32x4 acc[4][4] = {};
  float4 fa0, fa1, fa2, fa3;

  // prologue: stage tile 0 (A via regs, B via gload_lds)
  LOADA(0);
  STAGE_B(0);
  asm volatile("s_waitcnt vmcnt(0)" ::: "memory");
  WRITEA(0);
  asm volatile("s_waitcnt lgkmcnt(0)" ::: "memory");
  PHASE_BAR();

  int curA = 0;
  for (int T = 0; T < NKT; ++T) {
    int nxtA = 8192 - curA;
    bool pf = (T < NKT - 1);
    int ktu = (T + 1) * 64;
    // ---- kk0: B frags + A frags, MFMA ----
    bf16x8 b0[4], a0[4];
#pragma unroll
    for (int ni = 0; ni < 4; ++ni) b0[ni] = *(const bf16x8*)(&sm[bro + ni * 1024 + gx0 * 8]);
#pragma unroll
    for (int mi = 0; mi < 4; ++mi) a0[mi] = *(const bf16x8*)(&sm[curA + aro + mi * 1024 + gx0 * 8]);
    __builtin_amdgcn_s_setprio(1);
#pragma unroll
    for (int mi = 0; mi < 4; ++mi)
#pragma unroll
      for (int ni = 0; ni < 4; ++ni)
        acc[mi][ni] = __builtin_amdgcn_mfma_f32_16x16x32_bf16(a0[mi], b0[ni], acc[mi][ni], 0, 0, 0);
    __builtin_amdgcn_s_setprio(0);
    // ---- kk1 B reads must finish before B restage ----
    int gx1 = gx0 ^ 4;
    bf16x8 b1[4];
#pragma unroll
    for (int ni = 0; ni < 4; ++ni) b1[ni] = *(const bf16x8*)(&sm[bro + ni * 1024 + gx1 * 8]);
    LGKM0();
    PHASE_BAR();                       // every wave's B reads done -> B free
    if (pf) { STAGE_B(ktu); LOADA(ktu); }
    // ---- kk1: A frags + MFMA (A dbuf: no WAR with tail write) ----
    bf16x8 a1[4];
#pragma unroll
    for (int mi = 0; mi < 4; ++mi) a1[mi] = *(const bf16x8*)(&sm[curA + aro + mi * 1024 + gx1 * 8]);
    __builtin_amdgcn_s_setprio(1);
#pragma unroll
    for (int mi = 0; mi < 4; ++mi)
#pragma unroll
      for (int ni = 0; ni < 4; ++ni)
        acc[mi][ni] = __builtin_amdgcn_mfma_f32_16x16x32_bf16(a1[mi], b1[ni], acc[mi][ni], 0, 0, 0);
    __builtin_amdgcn_s_setprio(0);
    if (pf) {
      asm volatile("s_waitcnt vmcnt(0)" ::: "memory");   // B(T+1) landed, A regs ready
      WRITEA(nxtA);
      asm volatile("s_waitcnt lgkmcnt(0)" ::: "memory"); // ds_writes committed
      PHASE_BAR();
    }
    curA = nxtA;
  }

  // epilogue: bias + phi, bf16 stores
#pragma unroll
  for (int mi = 0; mi < 4; ++mi) {
#pragma unroll
    for (int ni = 0; ni < 4; ++ni) {
      int col = bcol0 + wc * 64 + ni * 16 + lr;
      float bb = bias[col];
#pragma unroll
      for (int i = 0; i < 4; ++i) {
        size_t row = arow0 + wr * 64 + mi * 16 + g4 * 4 + i;
        float v = acc[mi][ni][i] + bb;
        if (col < 1536) v = (v > 0.0f) ? (v + 1.0f) : __expf(v);
        C[row * TD_ + col] = f2bf(v);
      }
    }
  }
#undef STAGE_B
#undef LOADA
#undef WRITEA
}

// ---------------------------------------------------------------------------
// Attention core, one block per (b,h). Never materializes kv[192][192].
#define ALD 196  // LDS stride for 192-wide bf16 rows

__global__ __launch_bounds__(256) void k_attn(
    const u16* __restrict__ qkv,  // [M_,2304] bf16
    float* __restrict__ mt, float* __restrict__ mi)  // [B_,768] fp32
{
  __shared__ u16 qs[S_ * ALD];
  __shared__ u16 ks2[S_ * ALD];
  __shared__ float z[DH_], wt[S_], wi[S_], qt[DH_], qi[DH_], at[S_], ai[S_];
  int t = threadIdx.x;
  int b = blockIdx.x >> 2, h = blockIdx.x & 3;
  size_t base = (size_t)b * S_ * TD_;
  int qoff = h * DH_, koff = 768 + h * DH_, voff = 1536 + h * DH_;

  for (int idx = t; idx < S_ * 48; idx += 256) {
    int s = idx / 48, c = (idx % 48) * 4;
    *(ushort4*)(&qs[s * ALD + c])  = *(const ushort4*)(&qkv[base + (size_t)s * TD_ + qoff + c]);
    *(ushort4*)(&ks2[s * ALD + c]) = *(const ushort4*)(&qkv[base + (size_t)s * TD_ + koff + c]);
  }
  __syncthreads();
  if (t < DH_) {
    float a = 0;
    for (int s = 0; s < S_; ++s) a += bf2f(ks2[s * ALD + t]);
    z[t] = a;
  }
  __syncthreads();
  if (t < S_) {
    float a = 0;
    for (int d = 0; d < DH_; ++d) a += bf2f(qs[t * ALD + d]) * z[d];
    float den = a + 1e-6f;
    wt[t] = (t < TEXT_) ? 1.0f / (35.0f * den) : 0.0f;
    wi[t] = (t >= TEXT_) ? 1.0f / (36.0f * den) : 0.0f;
  }
  __syncthreads();
  if (t < DH_) {
    float aT = 0, aI = 0;
    for (int s = 0; s < S_; ++s) {
      float qv = bf2f(qs[s * ALD + t]);
      aT += qv * wt[s]; aI += qv * wi[s];
    }
    qt[t] = aT; qi[t] = aI;
  }
  __syncthreads();
  if (t < S_) {
    float aT = 0, aI = 0;
    for (int d = 0; d < DH_; ++d) {
      float kv = bf2f(ks2[t * ALD + d]);
      aT += kv * qt[d]; aI += kv * qi[d];
    }
    at[t] = aT; ai[t] = aI;
  }
  __syncthreads();
  if (t < DH_) {
    float aT = 0, aI = 0;
    for (int s = 0; s < S_; ++s) {
      float vv = bf2f(qkv[base + (size_t)s * TD_ + voff + t]);
      aT += at[s] * vv; aI += ai[s] * vv;
    }
    mt[(size_t)b * D_ + qoff + t] = aT;
    mi[(size_t)b * D_ + qoff + t] = aI;
  }
}

// ---------------------------------------------------------------------------
// Final head: f = m @ w_out^T + b_out ; r = tanh(f) ; cosine similarity.
#define GFIN 4
__global__ __launch_bounds__(256) void k_final(
    const float* __restrict__ mt, const float* __restrict__ mi,
    const float* __restrict__ wT,   // [768,768] = w_out transposed [d][e]
    const float* __restrict__ bout, // [768]
    float* __restrict__ out)        // [B_]
{
  __shared__ float mts[GFIN][768], mis[GFIN][768];
  __shared__ float red[3][4];
  int t = threadIdx.x, b0 = blockIdx.x * GFIN;
  for (int i = t; i < GFIN * 768; i += 256) {
    int g = i / 768, d = i % 768;
    mts[g][d] = mt[(size_t)(b0 + g) * 768 + d];
    mis[g][d] = mi[(size_t)(b0 + g) * 768 + d];
  }
  __syncthreads();
  float aT[GFIN][3] = {}, aI[GFIN][3] = {};
  for (int d = 0; d < 768; ++d) {
    const float* wrow = wT + (size_t)d * 768 + t;
    float w0 = wrow[0], w1 = wrow[256], w2 = wrow[512];
#pragma unroll
    for (int g = 0; g < GFIN; ++g) {
      float m1 = mts[g][d], m2 = mis[g][d];
      aT[g][0] += m1 * w0; aT[g][1] += m1 * w1; aT[g][2] += m1 * w2;
      aI[g][0] += m2 * w0; aI[g][1] += m2 * w1; aI[g][2] += m2 * w2;
    }
  }
  int lane = t & 63, wid = t >> 6;
  for (int g = 0; g < GFIN; ++g) {
    float st = 0, si = 0, sd = 0;
#pragma unroll
    for (int j = 0; j < 3; ++j) {
      float bo = bout[t + j * 256];
      float rt = tanhf(aT[g][j] + bo);
      float ri = tanhf(aI[g][j] + bo);
      st += rt * rt; si += ri * ri; sd += rt * ri;
    }
#pragma unroll
    for (int off = 32; off >= 1; off >>= 1) {
      st += __shfl_down(st, off);
      si += __shfl_down(si, off);
      sd += __shfl_down(sd, off);
    }
    __syncthreads();
    if (lane == 0) { red[0][wid] = st; red[1][wid] = si; red[2][wid] = sd; }
    __syncthreads();
    if (t == 0) {
      float S1 = red[0][0] + red[0][1] + red[0][2] + red[0][3];
      float S2 = red[1][0] + red[1][1] + red[1][2] + red[1][3];
      float S3 = red[2][0] + red[2][1] + red[2][2] + red[2][3];
      out[b0 + g] = S3 / (fmaxf(sqrtf(S1), 1e-8f) * fmaxf(sqrtf(S2), 1e-8f));
    }
  }
}

// ---------------------------------------------------------------------------
extern "C" void kernel_launch(void* const* d_in, const int* in_sizes, int n_in,
                              void* d_out, int out_size, void* d_ws, size_t ws_size,
                              hipStream_t stream) {
  const float* features = (const float*)d_in[0];
  // d_in[1] = attention_mask (unused by forward)
  const float* w_qkv = (const float*)d_in[2];
  const float* b_qkv = (const float*)d_in[3];
  const float* w_out = (const float*)d_in[4];
  const float* b_out = (const float*)d_in[5];
  float* out = (float*)d_out;

  char* ws = (char*)d_ws;
  size_t off = 0;
  auto alloc = [&](size_t bytes) {
    void* p = ws + off;
    off += (bytes + 255) & ~(size_t)255;
    return p;
  };
  u16* qkv  = (u16*)alloc((size_t)M_ * TD_ * 2);   // 670 MB
  u16* Wbf  = (u16*)alloc((size_t)TD_ * D_ * 2);   // 3.5 MB
  float* wT = (float*)alloc((size_t)D_ * D_ * 4);  // 2.4 MB
  float* mt = (float*)alloc((size_t)B_ * D_ * 4);  // 6.3 MB
  float* mi = (float*)alloc((size_t)B_ * D_ * 4);  // 6.3 MB
  (void)ws_size;

  hipLaunchKernelGGL(k_cvt_bf16, dim3((TD_ * D_ / 8 + 255) / 256), dim3(256), 0, stream,
                     w_qkv, Wbf, TD_ * D_ / 8);
  hipLaunchKernelGGL(k_transpose768, dim3(2304), dim3(256), 0, stream, w_out, wT);

  hipLaunchKernelGGL(k_gemm_qkv, dim3(9 * 1136), dim3(512), 0, stream,
                     features, Wbf, b_qkv, qkv);
  hipLaunchKernelGGL(k_attn, dim3(B_ * H_), dim3(256), 0, stream, qkv, mt, mi);
  hipLaunchKernelGGL(k_final, dim3(B_ / GFIN), dim3(256), 0, stream, mt, mi, wT, b_out, out);
}

// Round 12
// 1085.003 us; speedup vs baseline: 1.2227x; 1.2227x over previous
//
#include <hip/hip_runtime.h>
#include <hip/hip_bf16.h>

#define B_ 2048
#define S_ 71
#define D_ 768
#define H_ 4
#define DH_ 192
#define TD_ 2304            // 3*D
#define M_ (B_ * S_)        // 145408 = 1136*128
#define TEXT_ 35
#define NKT 12              // 768 / 64 K-tiles

typedef unsigned short u16;
typedef unsigned int u32;
typedef __attribute__((ext_vector_type(4))) float f32x4;
typedef __attribute__((ext_vector_type(8))) short bf16x8;

__device__ __forceinline__ u16 f2bf(float f) {
  u32 u = __float_as_uint(f);
  u32 r = (u + 0x7FFFu + ((u >> 16) & 1u)) >> 16;  // RNE
  return (u16)r;
}
__device__ __forceinline__ float bf2f(u16 x) {
  return __uint_as_float(((u32)x) << 16);
}
// packed fp32->bf16 RNE via COMPILER intrinsic (emits v_cvt_pk_bf16_f32;
// m240: hand-written inline-asm cvt_pk spills regs / blocks the scheduler)
__device__ __forceinline__ u32 pk2bf(float lo, float hi) {
  __hip_bfloat162 h = __float22bfloat162_rn(float2{lo, hi});
  return *reinterpret_cast<u32*>(&h);
}

typedef __attribute__((address_space(1))) const unsigned int GASU;
typedef __attribute__((address_space(3))) unsigned int LASU;
__device__ __forceinline__ void gload16(const void* g, void* l) {
  __builtin_amdgcn_global_load_lds((GASU*)g, (LASU*)l, 16, 0, 0);
}

#define PHASE_BAR() do { __builtin_amdgcn_s_barrier(); asm volatile("" ::: "memory"); } while (0)
#define LGKM0() do { asm volatile("s_waitcnt lgkmcnt(0)" ::: "memory"); __builtin_amdgcn_sched_barrier(0); } while (0)

// ---------------------------------------------------------------------------
// fp32 -> bf16 elementwise, 8 elems/thread, exact grid (used for w_qkv only)
__global__ __launch_bounds__(256) void k_cvt_bf16(const float* __restrict__ in,
                                                  u16* __restrict__ out, int n8) {
  int idx = blockIdx.x * 256 + threadIdx.x;
  if (idx >= n8) return;
  const float4* p = (const float4*)(in + (size_t)idx * 8);
  float4 a = p[0], b = p[1];
  uint4 o;
  o.x = pk2bf(a.x, a.y);
  o.y = pk2bf(a.z, a.w);
  o.z = pk2bf(b.x, b.y);
  o.w = pk2bf(b.z, b.w);
  *(uint4*)(out + (size_t)idx * 8) = o;
}

// ---------------------------------------------------------------------------
// w_out [e][d] -> w_outT [d][e]  (768x768 fp32, tiny)
__global__ void k_transpose768(const float* __restrict__ in, float* __restrict__ out) {
  int idx = blockIdx.x * 256 + threadIdx.x;
  int e = idx / 768, d = idx % 768;
  out[(size_t)d * 768 + e] = in[idx];
}

// ---------------------------------------------------------------------------
// GEMM: C[M,2304] = A[M,768](fp32, converted in-kernel) * Bw[2304,768](bf16),
// bias + phi epilogue. 128x256 tile, BK=64, 8 waves 64x64, A dbuf (2x16KB) +
// B single (32KB) = 64KB LDS, launch_bounds(512,4) -> 2 blocks/CU.
// A REG-STAGED fp32->bf16 via __float22bfloat162_rn (compiler emits
// v_cvt_pk_bf16_f32; round-10's manual bit-RNE was VALU-heavy, round-11's
// inline-asm spilled to scratch).
__global__ __launch_bounds__(512, 4) void k_gemm_qkv(
    const float* __restrict__ Afp,  // [M_,768] fp32 (features)
    const u16* __restrict__ Bw,     // [2304,768] bf16 (n-major)
    const float* __restrict__ bias, // [2304]
    u16* __restrict__ C)            // [M_,2304] bf16, phi on cols<1536
{
  // u16 units: A0 [0,8192), A1 [8192,16384), B [16384,32768)
  __shared__ u16 sm[32768];   // 64 KiB
  int t = threadIdx.x;
  int lane = t & 63, wid = t >> 6;
  int wr = wid >> 2, wc = wid & 3;     // 2 x 4 wave grid, wave tile 64x64
  int lr = lane & 15;
  int g4 = lane >> 4;

  // XCD-bijective swizzle: nwg = 10224 = 8*1278; bn inner -> A-panel L2 reuse
  int swz = (blockIdx.x & 7) * 1278 + (blockIdx.x >> 3);
  int bm = swz / 9, bn = swz % 9;
  const size_t arow0 = (size_t)bm * 128;
  const int bcol0 = bn * 256;

  // A: 1024 granule-chunks (8 elems), 2/thread. chunk c: row=c>>3, source
  // granule pre-swizzled (c&7)^(row&7); LDS dst linear c*8 (u16).
  const float* srcAf[2];
  int dA[2];
#pragma unroll
  for (int j = 0; j < 2; ++j) {
    int c = j * 512 + t;
    srcAf[j] = Afp + (arow0 + (c >> 3)) * 768 + ((c & 7) ^ ((c >> 3) & 7)) * 8;
    dA[j] = c * 8;
  }
  // B: gload_lds, 2048 chunks, 4/thread (same pre-swizzled source)
  const u16* srcB[4];
  int dB[4];
#pragma unroll
  for (int j = 0; j < 4; ++j) {
    int c = j * 512 + t;
    srcB[j] = Bw + (size_t)(bcol0 + (c >> 3)) * 768 + ((c & 7) ^ ((c >> 3) & 7)) * 8;
    dB[j] = 16384 + c * 8;
  }

#define STAGE_B(ktu) do { \
  gload16(srcB[0] + (ktu), &sm[dB[0]]); \
  gload16(srcB[1] + (ktu), &sm[dB[1]]); \
  gload16(srcB[2] + (ktu), &sm[dB[2]]); \
  gload16(srcB[3] + (ktu), &sm[dB[3]]); \
} while (0)
#define LOADA(ktu) do { \
  fa0 = *(const float4*)(srcAf[0] + (ktu)); \
  fa1 = *(const float4*)(srcAf[0] + (ktu) + 4); \
  fa2 = *(const float4*)(srcAf[1] + (ktu)); \
  fa3 = *(const float4*)(srcAf[1] + (ktu) + 4); \
} while (0)
#define WRITEA(abuf) do { \
  uint4 o0; \
  o0.x = pk2bf(fa0.x, fa0.y); o0.y = pk2bf(fa0.z, fa0.w); \
  o0.z = pk2bf(fa1.x, fa1.y); o0.w = pk2bf(fa1.z, fa1.w); \
  *(uint4*)(&sm[(abuf) + dA[0]]) = o0; \
  uint4 o1; \
  o1.x = pk2bf(fa2.x, fa2.y); o1.y = pk2bf(fa2.z, fa2.w); \
  o1.z = pk2bf(fa3.x, fa3.y); o1.w = pk2bf(fa3.z, fa3.w); \
  *(uint4*)(&sm[(abuf) + dA[1]]) = o1; \
} while (0)

  // fragment addresses (swizzled read side)
  int gx0 = g4 ^ (lr & 7);             // kk=0 granule; kk=1 -> gx0^4
  int aro = (wr * 64 + lr) * 64;       // + mi*1024 + gx*8  (u16)
  int bro = 16384 + (wc * 64 + lr) * 64;

  f32x4 acc[4][4] = {};
  float4 fa0, fa1, fa2, fa3;

  // prologue: stage tile 0 (A via regs, B via gload_lds)
  LOADA(0);
  STAGE_B(0);
  asm volatile("s_waitcnt vmcnt(0)" ::: "memory");
  WRITEA(0);
  asm volatile("s_waitcnt lgkmcnt(0)" ::: "memory");
  PHASE_BAR();

  int curA = 0;
  for (int T = 0; T < NKT; ++T) {
    int nxtA = 8192 - curA;
    bool pf = (T < NKT - 1);
    int ktu = (T + 1) * 64;
    // ---- kk0: B frags + A frags, MFMA ----
    bf16x8 b0[4], a0[4];
#pragma unroll
    for (int ni = 0; ni < 4; ++ni) b0[ni] = *(const bf16x8*)(&sm[bro + ni * 1024 + gx0 * 8]);
#pragma unroll
    for (int mi = 0; mi < 4; ++mi) a0[mi] = *(const bf16x8*)(&sm[curA + aro + mi * 1024 + gx0 * 8]);
    __builtin_amdgcn_s_setprio(1);
#pragma unroll
    for (int mi = 0; mi < 4; ++mi)
#pragma unroll
      for (int ni = 0; ni < 4; ++ni)
        acc[mi][ni] = __builtin_amdgcn_mfma_f32_16x16x32_bf16(a0[mi], b0[ni], acc[mi][ni], 0, 0, 0);
    __builtin_amdgcn_s_setprio(0);
    // ---- kk1 B reads must finish before B restage ----
    int gx1 = gx0 ^ 4;
    bf16x8 b1[4];
#pragma unroll
    for (int ni = 0; ni < 4; ++ni) b1[ni] = *(const bf16x8*)(&sm[bro + ni * 1024 + gx1 * 8]);
    LGKM0();
    PHASE_BAR();                       // every wave's B reads done -> B free
    if (pf) { STAGE_B(ktu); LOADA(ktu); }
    // ---- kk1: A frags + MFMA (A dbuf: no WAR with tail write) ----
    bf16x8 a1[4];
#pragma unroll
    for (int mi = 0; mi < 4; ++mi) a1[mi] = *(const bf16x8*)(&sm[curA + aro + mi * 1024 + gx1 * 8]);
    __builtin_amdgcn_s_setprio(1);
#pragma unroll
    for (int mi = 0; mi < 4; ++mi)
#pragma unroll
      for (int ni = 0; ni < 4; ++ni)
        acc[mi][ni] = __builtin_amdgcn_mfma_f32_16x16x32_bf16(a1[mi], b1[ni], acc[mi][ni], 0, 0, 0);
    __builtin_amdgcn_s_setprio(0);
    if (pf) {
      asm volatile("s_waitcnt vmcnt(0)" ::: "memory");   // B(T+1) landed, A regs ready
      WRITEA(nxtA);
      asm volatile("s_waitcnt lgkmcnt(0)" ::: "memory"); // ds_writes committed
      PHASE_BAR();
    }
    curA = nxtA;
  }

  // epilogue: bias + phi, bf16 stores
#pragma unroll
  for (int mi = 0; mi < 4; ++mi) {
#pragma unroll
    for (int ni = 0; ni < 4; ++ni) {
      int col = bcol0 + wc * 64 + ni * 16 + lr;
      float bb = bias[col];
#pragma unroll
      for (int i = 0; i < 4; ++i) {
        size_t row = arow0 + wr * 64 + mi * 16 + g4 * 4 + i;
        float v = acc[mi][ni][i] + bb;
        if (col < 1536) v = (v > 0.0f) ? (v + 1.0f) : __expf(v);
        C[row * TD_ + col] = f2bf(v);
      }
    }
  }
#undef STAGE_B
#undef LOADA
#undef WRITEA
}

// ---------------------------------------------------------------------------
// Attention core, one block per (b,h). Never materializes kv[192][192].
#define ALD 196  // LDS stride for 192-wide bf16 rows

__global__ __launch_bounds__(256) void k_attn(
    const u16* __restrict__ qkv,  // [M_,2304] bf16
    float* __restrict__ mt, float* __restrict__ mi)  // [B_,768] fp32
{
  __shared__ u16 qs[S_ * ALD];
  __shared__ u16 ks2[S_ * ALD];
  __shared__ float z[DH_], wt[S_], wi[S_], qt[DH_], qi[DH_], at[S_], ai[S_];
  int t = threadIdx.x;
  int b = blockIdx.x >> 2, h = blockIdx.x & 3;
  size_t base = (size_t)b * S_ * TD_;
  int qoff = h * DH_, koff = 768 + h * DH_, voff = 1536 + h * DH_;

  for (int idx = t; idx < S_ * 48; idx += 256) {
    int s = idx / 48, c = (idx % 48) * 4;
    *(ushort4*)(&qs[s * ALD + c])  = *(const ushort4*)(&qkv[base + (size_t)s * TD_ + qoff + c]);
    *(ushort4*)(&ks2[s * ALD + c]) = *(const ushort4*)(&qkv[base + (size_t)s * TD_ + koff + c]);
  }
  __syncthreads();
  if (t < DH_) {
    float a = 0;
    for (int s = 0; s < S_; ++s) a += bf2f(ks2[s * ALD + t]);
    z[t] = a;
  }
  __syncthreads();
  if (t < S_) {
    float a = 0;
    for (int d = 0; d < DH_; ++d) a += bf2f(qs[t * ALD + d]) * z[d];
    float den = a + 1e-6f;
    wt[t] = (t < TEXT_) ? 1.0f / (35.0f * den) : 0.0f;
    wi[t] = (t >= TEXT_) ? 1.0f / (36.0f * den) : 0.0f;
  }
  __syncthreads();
  if (t < DH_) {
    float aT = 0, aI = 0;
    for (int s = 0; s < S_; ++s) {
      float qv = bf2f(qs[s * ALD + t]);
      aT += qv * wt[s]; aI += qv * wi[s];
    }
    qt[t] = aT; qi[t] = aI;
  }
  __syncthreads();
  if (t < S_) {
    float aT = 0, aI = 0;
    for (int d = 0; d < DH_; ++d) {
      float kv = bf2f(ks2[t * ALD + d]);
      aT += kv * qt[d]; aI += kv * qi[d];
    }
    at[t] = aT; ai[t] = aI;
  }
  __syncthreads();
  if (t < DH_) {
    float aT = 0, aI = 0;
    for (int s = 0; s < S_; ++s) {
      float vv = bf2f(qkv[base + (size_t)s * TD_ + voff + t]);
      aT += at[s] * vv; aI += ai[s] * vv;
    }
    mt[(size_t)b * D_ + qoff + t] = aT;
    mi[(size_t)b * D_ + qoff + t] = aI;
  }
}

// ---------------------------------------------------------------------------
// Final head: f = m @ w_out^T + b_out ; r = tanh(f) ; cosine similarity.
#define GFIN 4
__global__ __launch_bounds__(256) void k_final(
    const float* __restrict__ mt, const float* __restrict__ mi,
    const float* __restrict__ wT,   // [768,768] = w_out transposed [d][e]
    const float* __restrict__ bout, // [768]
    float* __restrict__ out)        // [B_]
{
  __shared__ float mts[GFIN][768], mis[GFIN][768];
  __shared__ float red[3][4];
  int t = threadIdx.x, b0 = blockIdx.x * GFIN;
  for (int i = t; i < GFIN * 768; i += 256) {
    int g = i / 768, d = i % 768;
    mts[g][d] = mt[(size_t)(b0 + g) * 768 + d];
    mis[g][d] = mi[(size_t)(b0 + g) * 768 + d];
  }
  __syncthreads();
  float aT[GFIN][3] = {}, aI[GFIN][3] = {};
  for (int d = 0; d < 768; ++d) {
    const float* wrow = wT + (size_t)d * 768 + t;
    float w0 = wrow[0], w1 = wrow[256], w2 = wrow[512];
#pragma unroll
    for (int g = 0; g < GFIN; ++g) {
      float m1 = mts[g][d], m2 = mis[g][d];
      aT[g][0] += m1 * w0; aT[g][1] += m1 * w1; aT[g][2] += m1 * w2;
      aI[g][0] += m2 * w0; aI[g][1] += m2 * w1; aI[g][2] += m2 * w2;
    }
  }
  int lane = t & 63, wid = t >> 6;
  for (int g = 0; g < GFIN; ++g) {
    float st = 0, si = 0, sd = 0;
#pragma unroll
    for (int j = 0; j < 3; ++j) {
      float bo = bout[t + j * 256];
      float rt = tanhf(aT[g][j] + bo);
      float ri = tanhf(aI[g][j] + bo);
      st += rt * rt; si += ri * ri; sd += rt * ri;
    }
#pragma unroll
    for (int off = 32; off >= 1; off >>= 1) {
      st += __shfl_down(st, off);
      si += __shfl_down(si, off);
      sd += __shfl_down(sd, off);
    }
    __syncthreads();
    if (lane == 0) { red[0][wid] = st; red[1][wid] = si; red[2][wid] = sd; }
    __syncthreads();
    if (t == 0) {
      float S1 = red[0][0] + red[0][1] + red[0][2] + red[0][3];
      float S2 = red[1][0] + red[1][1] + red[1][2] + red[1][3];
      float S3 = red[2][0] + red[2][1] + red[2][2] + red[2][3];
      out[b0 + g] = S3 / (fmaxf(sqrtf(S1), 1e-8f) * fmaxf(sqrtf(S2), 1e-8f));
    }
  }
}

// ---------------------------------------------------------------------------
extern "C" void kernel_launch(void* const* d_in, const int* in_sizes, int n_in,
                              void* d_out, int out_size, void* d_ws, size_t ws_size,
                              hipStream_t stream) {
  const float* features = (const float*)d_in[0];
  // d_in[1] = attention_mask (unused by forward)
  const float* w_qkv = (const float*)d_in[2];
  const float* b_qkv = (const float*)d_in[3];
  const float* w_out = (const float*)d_in[4];
  const float* b_out = (const float*)d_in[5];
  float* out = (float*)d_out;

  char* ws = (char*)d_ws;
  size_t off = 0;
  auto alloc = [&](size_t bytes) {
    void* p = ws + off;
    off += (bytes + 255) & ~(size_t)255;
    return p;
  };
  u16* qkv  = (u16*)alloc((size_t)M_ * TD_ * 2);   // 670 MB
  u16* Wbf  = (u16*)alloc((size_t)TD_ * D_ * 2);   // 3.5 MB
  float* wT = (float*)alloc((size_t)D_ * D_ * 4);  // 2.4 MB
  float* mt = (float*)alloc((size_t)B_ * D_ * 4);  // 6.3 MB
  float* mi = (float*)alloc((size_t)B_ * D_ * 4);  // 6.3 MB
  (void)ws_size;

  hipLaunchKernelGGL(k_cvt_bf16, dim3((TD_ * D_ / 8 + 255) / 256), dim3(256), 0, stream,
                     w_qkv, Wbf, TD_ * D_ / 8);
  hipLaunchKernelGGL(k_transpose768, dim3(2304), dim3(256), 0, stream, w_out, wT);

  hipLaunchKernelGGL(k_gemm_qkv, dim3(9 * 1136), dim3(512), 0, stream,
                     features, Wbf, b_qkv, qkv);
  hipLaunchKernelGGL(k_attn, dim3(B_ * H_), dim3(256), 0, stream, qkv, mt, mi);
  hipLaunchKernelGGL(k_final, dim3(B_ / GFIN), dim3(256), 0, stream, mt, mi, wT, b_out, out);
}

// Round 13
// 1072.337 us; speedup vs baseline: 1.2371x; 1.0118x over previous
//
#include <hip/hip_runtime.h>
#include <hip/hip_bf16.h>

#define B_ 2048
#define S_ 71
#define D_ 768
#define H_ 4
#define DH_ 192
#define TD_ 2304            // 3*D
#define M_ (B_ * S_)        // 145408 = 1136*128
#define TEXT_ 35
#define NKT 12              // 768 / 64 K-tiles

typedef unsigned short u16;
typedef unsigned int u32;
typedef __attribute__((ext_vector_type(4))) float f32x4;
typedef __attribute__((ext_vector_type(8))) short bf16x8;

__device__ __forceinline__ u16 f2bf(float f) {
  u32 u = __float_as_uint(f);
  u32 r = (u + 0x7FFFu + ((u >> 16) & 1u)) >> 16;  // RNE
  return (u16)r;
}
__device__ __forceinline__ float bf2f(u16 x) {
  return __uint_as_float(((u32)x) << 16);
}
// packed fp32->bf16 RNE via COMPILER intrinsic (emits v_cvt_pk_bf16_f32;
// round 11 proved inline-asm cvt_pk spills regs at a tight VGPR cap)
__device__ __forceinline__ u32 pk2bf(float lo, float hi) {
  __hip_bfloat162 h = __float22bfloat162_rn(float2{lo, hi});
  return *reinterpret_cast<u32*>(&h);
}

typedef __attribute__((address_space(1))) const unsigned int GASU;
typedef __attribute__((address_space(3))) unsigned int LASU;
__device__ __forceinline__ void gload16(const void* g, void* l) {
  __builtin_amdgcn_global_load_lds((GASU*)g, (LASU*)l, 16, 0, 0);
}

#define PHASE_BAR() do { __builtin_amdgcn_s_barrier(); asm volatile("" ::: "memory"); } while (0)
#define LGKM0() do { asm volatile("s_waitcnt lgkmcnt(0)" ::: "memory"); __builtin_amdgcn_sched_barrier(0); } while (0)

// ---------------------------------------------------------------------------
// fp32 -> bf16 elementwise, 8 elems/thread, exact grid (used for w_qkv only)
__global__ __launch_bounds__(256) void k_cvt_bf16(const float* __restrict__ in,
                                                  u16* __restrict__ out, int n8) {
  int idx = blockIdx.x * 256 + threadIdx.x;
  if (idx >= n8) return;
  const float4* p = (const float4*)(in + (size_t)idx * 8);
  float4 a = p[0], b = p[1];
  uint4 o;
  o.x = pk2bf(a.x, a.y);
  o.y = pk2bf(a.z, a.w);
  o.z = pk2bf(b.x, b.y);
  o.w = pk2bf(b.z, b.w);
  *(uint4*)(out + (size_t)idx * 8) = o;
}

// ---------------------------------------------------------------------------
// w_out [e][d] -> w_outT [d][e]  (768x768 fp32, tiny)
__global__ void k_transpose768(const float* __restrict__ in, float* __restrict__ out) {
  int idx = blockIdx.x * 256 + threadIdx.x;
  int e = idx / 768, d = idx % 768;
  out[(size_t)d * 768 + e] = in[idx];
}

// ---------------------------------------------------------------------------
// GEMM: C[M,2304] = A[M,768](fp32, converted in-kernel) * Bw[2304,768](bf16),
// bias + phi epilogue. 128x256 tile, BK=64, 8 waves 64x64, A dbuf (2x16KB) +
// B single (32KB) = 64KB LDS, launch_bounds(512,4) -> 2 blocks/CU.
// A REG-STAGED fp32->bf16 via __float22bfloat162_rn.
__global__ __launch_bounds__(512, 4) void k_gemm_qkv(
    const float* __restrict__ Afp,  // [M_,768] fp32 (features)
    const u16* __restrict__ Bw,     // [2304,768] bf16 (n-major)
    const float* __restrict__ bias, // [2304]
    u16* __restrict__ C)            // [M_,2304] bf16, phi on cols<1536
{
  // u16 units: A0 [0,8192), A1 [8192,16384), B [16384,32768)
  __shared__ u16 sm[32768];   // 64 KiB
  int t = threadIdx.x;
  int lane = t & 63, wid = t >> 6;
  int wr = wid >> 2, wc = wid & 3;     // 2 x 4 wave grid, wave tile 64x64
  int lr = lane & 15;
  int g4 = lane >> 4;

  // XCD-bijective swizzle: nwg = 10224 = 8*1278; bn inner -> A-panel L2 reuse
  int swz = (blockIdx.x & 7) * 1278 + (blockIdx.x >> 3);
  int bm = swz / 9, bn = swz % 9;
  const size_t arow0 = (size_t)bm * 128;
  const int bcol0 = bn * 256;

  // A: 1024 granule-chunks (8 elems), 2/thread. chunk c: row=c>>3, source
  // granule pre-swizzled (c&7)^(row&7); LDS dst linear c*8 (u16).
  const float* srcAf[2];
  int dA[2];
#pragma unroll
  for (int j = 0; j < 2; ++j) {
    int c = j * 512 + t;
    srcAf[j] = Afp + (arow0 + (c >> 3)) * 768 + ((c & 7) ^ ((c >> 3) & 7)) * 8;
    dA[j] = c * 8;
  }
  // B: gload_lds, 2048 chunks, 4/thread (same pre-swizzled source)
  const u16* srcB[4];
  int dB[4];
#pragma unroll
  for (int j = 0; j < 4; ++j) {
    int c = j * 512 + t;
    srcB[j] = Bw + (size_t)(bcol0 + (c >> 3)) * 768 + ((c & 7) ^ ((c >> 3) & 7)) * 8;
    dB[j] = 16384 + c * 8;
  }

#define STAGE_B(ktu) do { \
  gload16(srcB[0] + (ktu), &sm[dB[0]]); \
  gload16(srcB[1] + (ktu), &sm[dB[1]]); \
  gload16(srcB[2] + (ktu), &sm[dB[2]]); \
  gload16(srcB[3] + (ktu), &sm[dB[3]]); \
} while (0)
#define LOADA(ktu) do { \
  fa0 = *(const float4*)(srcAf[0] + (ktu)); \
  fa1 = *(const float4*)(srcAf[0] + (ktu) + 4); \
  fa2 = *(const float4*)(srcAf[1] + (ktu)); \
  fa3 = *(const float4*)(srcAf[1] + (ktu) + 4); \
} while (0)
#define WRITEA(abuf) do { \
  uint4 o0; \
  o0.x = pk2bf(fa0.x, fa0.y); o0.y = pk2bf(fa0.z, fa0.w); \
  o0.z = pk2bf(fa1.x, fa1.y); o0.w = pk2bf(fa1.z, fa1.w); \
  *(uint4*)(&sm[(abuf) + dA[0]]) = o0; \
  uint4 o1; \
  o1.x = pk2bf(fa2.x, fa2.y); o1.y = pk2bf(fa2.z, fa2.w); \
  o1.z = pk2bf(fa3.x, fa3.y); o1.w = pk2bf(fa3.z, fa3.w); \
  *(uint4*)(&sm[(abuf) + dA[1]]) = o1; \
} while (0)

  // fragment addresses (swizzled read side)
  int gx0 = g4 ^ (lr & 7);             // kk=0 granule; kk=1 -> gx0^4
  int aro = (wr * 64 + lr) * 64;       // + mi*1024 + gx*8  (u16)
  int bro = 16384 + (wc * 64 + lr) * 64;

  f32x4 acc[4][4] = {};
  float4 fa0, fa1, fa2, fa3;

  // prologue: stage tile 0 (A via regs, B via gload_lds)
  LOADA(0);
  STAGE_B(0);
  asm volatile("s_waitcnt vmcnt(0)" ::: "memory");
  WRITEA(0);
  asm volatile("s_waitcnt lgkmcnt(0)" ::: "memory");
  PHASE_BAR();

  int curA = 0;
  for (int T = 0; T < NKT; ++T) {
    int nxtA = 8192 - curA;
    bool pf = (T < NKT - 1);
    int ktu = (T + 1) * 64;
    // ---- kk0: B frags + A frags, MFMA ----
    bf16x8 b0[4], a0[4];
#pragma unroll
    for (int ni = 0; ni < 4; ++ni) b0[ni] = *(const bf16x8*)(&sm[bro + ni * 1024 + gx0 * 8]);
#pragma unroll
    for (int mi = 0; mi < 4; ++mi) a0[mi] = *(const bf16x8*)(&sm[curA + aro + mi * 1024 + gx0 * 8]);
    __builtin_amdgcn_s_setprio(1);
#pragma unroll
    for (int mi = 0; mi < 4; ++mi)
#pragma unroll
      for (int ni = 0; ni < 4; ++ni)
        acc[mi][ni] = __builtin_amdgcn_mfma_f32_16x16x32_bf16(a0[mi], b0[ni], acc[mi][ni], 0, 0, 0);
    __builtin_amdgcn_s_setprio(0);
    // ---- kk1 B reads must finish before B restage ----
    int gx1 = gx0 ^ 4;
    bf16x8 b1[4];
#pragma unroll
    for (int ni = 0; ni < 4; ++ni) b1[ni] = *(const bf16x8*)(&sm[bro + ni * 1024 + gx1 * 8]);
    LGKM0();
    PHASE_BAR();                       // every wave's B reads done -> B free
    if (pf) { STAGE_B(ktu); LOADA(ktu); }
    // ---- kk1: A frags + MFMA (A dbuf: no WAR with tail write) ----
    bf16x8 a1[4];
#pragma unroll
    for (int mi = 0; mi < 4; ++mi) a1[mi] = *(const bf16x8*)(&sm[curA + aro + mi * 1024 + gx1 * 8]);
    __builtin_amdgcn_s_setprio(1);
#pragma unroll
    for (int mi = 0; mi < 4; ++mi)
#pragma unroll
      for (int ni = 0; ni < 4; ++ni)
        acc[mi][ni] = __builtin_amdgcn_mfma_f32_16x16x32_bf16(a1[mi], b1[ni], acc[mi][ni], 0, 0, 0);
    __builtin_amdgcn_s_setprio(0);
    if (pf) {
      asm volatile("s_waitcnt vmcnt(0)" ::: "memory");   // B(T+1) landed, A regs ready
      WRITEA(nxtA);
      asm volatile("s_waitcnt lgkmcnt(0)" ::: "memory"); // ds_writes committed
      PHASE_BAR();
    }
    curA = nxtA;
  }

  // epilogue: bias + phi, bf16 stores
#pragma unroll
  for (int mi = 0; mi < 4; ++mi) {
#pragma unroll
    for (int ni = 0; ni < 4; ++ni) {
      int col = bcol0 + wc * 64 + ni * 16 + lr;
      float bb = bias[col];
#pragma unroll
      for (int i = 0; i < 4; ++i) {
        size_t row = arow0 + wr * 64 + mi * 16 + g4 * 4 + i;
        float v = acc[mi][ni][i] + bb;
        if (col < 1536) v = (v > 0.0f) ? (v + 1.0f) : __expf(v);
        C[row * TD_ + col] = f2bf(v);
      }
    }
  }
#undef STAGE_B
#undef LOADA
#undef WRITEA
}

// ---------------------------------------------------------------------------
// Attention core, one block per (b,h). Wave-parallelized: the S x D dot
// phases (den, at) run as 16 groups of 16 lanes (lane covers 12 d-elems,
// 4-step shfl_xor reduce) instead of 71 threads x 192 serial iterations.
// ALD=194: row stride 97 dwords == 1 mod 32 -> adjacent group rows hit
// disjoint bank parity (2-way max = free, m136).
#define ALD 194

__global__ __launch_bounds__(256) void k_attn(
    const u16* __restrict__ qkv,  // [M_,2304] bf16
    float* __restrict__ mt, float* __restrict__ mi)  // [B_,768] fp32
{
  __shared__ u16 qs[S_ * ALD];
  __shared__ u16 ks2[S_ * ALD];
  __shared__ float z[DH_], wt[S_], wi[S_], qt[DH_], qi[DH_], at[S_], ai[S_];
  int t = threadIdx.x;
  int b = blockIdx.x >> 2, h = blockIdx.x & 3;
  size_t base = (size_t)b * S_ * TD_;
  int qoff = h * DH_, koff = 768 + h * DH_, voff = 1536 + h * DH_;

  for (int idx = t; idx < S_ * 48; idx += 256) {
    int s = idx / 48, c = (idx % 48) * 4;
    *(ushort4*)(&qs[s * ALD + c])  = *(const ushort4*)(&qkv[base + (size_t)s * TD_ + qoff + c]);
    *(ushort4*)(&ks2[s * ALD + c]) = *(const ushort4*)(&qkv[base + (size_t)s * TD_ + koff + c]);
  }
  __syncthreads();
  // z[d] = sum_s k[s,d]   (192 threads, 71 iters)
  if (t < DH_) {
    float a = 0;
    for (int s = 0; s < S_; ++s) a += bf2f(ks2[s * ALD + t]);
    z[t] = a;
  }
  __syncthreads();
  // den[s] = q[s,:].z  — group-parallel (16 groups x 16 lanes x 12 elems)
  int grp = t >> 4, gl = t & 15;
  for (int s = grp; s < S_; s += 16) {
    float a = 0;
    int d0 = gl * 12;
#pragma unroll
    for (int i = 0; i < 12; ++i) a += bf2f(qs[s * ALD + d0 + i]) * z[d0 + i];
#pragma unroll
    for (int o = 8; o >= 1; o >>= 1) a += __shfl_xor(a, o);
    if (gl == 0) {
      float den = a + 1e-6f;
      wt[s] = (s < TEXT_) ? 1.0f / (35.0f * den) : 0.0f;
      wi[s] = (s >= TEXT_) ? 1.0f / (36.0f * den) : 0.0f;
    }
  }
  __syncthreads();
  // qt[d], qi[d] = sum_s q[s,d] * w[s]   (192 threads, 71 iters)
  if (t < DH_) {
    float aT = 0, aI = 0;
    for (int s = 0; s < S_; ++s) {
      float qv = bf2f(qs[s * ALD + t]);
      aT += qv * wt[s]; aI += qv * wi[s];
    }
    qt[t] = aT; qi[t] = aI;
  }
  __syncthreads();
  // at[s], ai[s] = k[s,:].qt / .qi — group-parallel
  for (int s = grp; s < S_; s += 16) {
    float aT = 0, aI = 0;
    int d0 = gl * 12;
#pragma unroll
    for (int i = 0; i < 12; ++i) {
      float kv = bf2f(ks2[s * ALD + d0 + i]);
      aT += kv * qt[d0 + i]; aI += kv * qi[d0 + i];
    }
#pragma unroll
    for (int o = 8; o >= 1; o >>= 1) { aT += __shfl_xor(aT, o); aI += __shfl_xor(aI, o); }
    if (gl == 0) { at[s] = aT; ai[s] = aI; }
  }
  __syncthreads();
  // m[e] = sum_s a[s] * v[s,e]   (192 threads, 71 coalesced global reads)
  if (t < DH_) {
    float aT = 0, aI = 0;
    for (int s = 0; s < S_; ++s) {
      float vv = bf2f(qkv[base + (size_t)s * TD_ + voff + t]);
      aT += at[s] * vv; aI += ai[s] * vv;
    }
    mt[(size_t)b * D_ + qoff + t] = aT;
    mi[(size_t)b * D_ + qoff + t] = aI;
  }
}

// ---------------------------------------------------------------------------
// Final head: f = m @ w_out^T + b_out ; r = tanh(f) ; cosine similarity.
#define GFIN 4
__global__ __launch_bounds__(256) void k_final(
    const float* __restrict__ mt, const float* __restrict__ mi,
    const float* __restrict__ wT,   // [768,768] = w_out transposed [d][e]
    const float* __restrict__ bout, // [768]
    float* __restrict__ out)        // [B_]
{
  __shared__ float mts[GFIN][768], mis[GFIN][768];
  __shared__ float red[3][4];
  int t = threadIdx.x, b0 = blockIdx.x * GFIN;
  for (int i = t; i < GFIN * 768; i += 256) {
    int g = i / 768, d = i % 768;
    mts[g][d] = mt[(size_t)(b0 + g) * 768 + d];
    mis[g][d] = mi[(size_t)(b0 + g) * 768 + d];
  }
  __syncthreads();
  float aT[GFIN][3] = {}, aI[GFIN][3] = {};
  for (int d = 0; d < 768; ++d) {
    const float* wrow = wT + (size_t)d * 768 + t;
    float w0 = wrow[0], w1 = wrow[256], w2 = wrow[512];
#pragma unroll
    for (int g = 0; g < GFIN; ++g) {
      float m1 = mts[g][d], m2 = mis[g][d];
      aT[g][0] += m1 * w0; aT[g][1] += m1 * w1; aT[g][2] += m1 * w2;
      aI[g][0] += m2 * w0; aI[g][1] += m2 * w1; aI[g][2] += m2 * w2;
    }
  }
  int lane = t & 63, wid = t >> 6;
  for (int g = 0; g < GFIN; ++g) {
    float st = 0, si = 0, sd = 0;
#pragma unroll
    for (int j = 0; j < 3; ++j) {
      float bo = bout[t + j * 256];
      float rt = tanhf(aT[g][j] + bo);
      float ri = tanhf(aI[g][j] + bo);
      st += rt * rt; si += ri * ri; sd += rt * ri;
    }
#pragma unroll
    for (int off = 32; off >= 1; off >>= 1) {
      st += __shfl_down(st, off);
      si += __shfl_down(si, off);
      sd += __shfl_down(sd, off);
    }
    __syncthreads();
    if (lane == 0) { red[0][wid] = st; red[1][wid] = si; red[2][wid] = sd; }
    __syncthreads();
    if (t == 0) {
      float S1 = red[0][0] + red[0][1] + red[0][2] + red[0][3];
      float S2 = red[1][0] + red[1][1] + red[1][2] + red[1][3];
      float S3 = red[2][0] + red[2][1] + red[2][2] + red[2][3];
      out[b0 + g] = S3 / (fmaxf(sqrtf(S1), 1e-8f) * fmaxf(sqrtf(S2), 1e-8f));
    }
  }
}

// ---------------------------------------------------------------------------
extern "C" void kernel_launch(void* const* d_in, const int* in_sizes, int n_in,
                              void* d_out, int out_size, void* d_ws, size_t ws_size,
                              hipStream_t stream) {
  const float* features = (const float*)d_in[0];
  // d_in[1] = attention_mask (unused by forward)
  const float* w_qkv = (const float*)d_in[2];
  const float* b_qkv = (const float*)d_in[3];
  const float* w_out = (const float*)d_in[4];
  const float* b_out = (const float*)d_in[5];
  float* out = (float*)d_out;

  char* ws = (char*)d_ws;
  size_t off = 0;
  auto alloc = [&](size_t bytes) {
    void* p = ws + off;
    off += (bytes + 255) & ~(size_t)255;
    return p;
  };
  u16* qkv  = (u16*)alloc((size_t)M_ * TD_ * 2);   // 670 MB
  u16* Wbf  = (u16*)alloc((size_t)TD_ * D_ * 2);   // 3.5 MB
  float* wT = (float*)alloc((size_t)D_ * D_ * 4);  // 2.4 MB
  float* mt = (float*)alloc((size_t)B_ * D_ * 4);  // 6.3 MB
  float* mi = (float*)alloc((size_t)B_ * D_ * 4);  // 6.3 MB
  (void)ws_size;

  hipLaunchKernelGGL(k_cvt_bf16, dim3((TD_ * D_ / 8 + 255) / 256), dim3(256), 0, stream,
                     w_qkv, Wbf, TD_ * D_ / 8);
  hipLaunchKernelGGL(k_transpose768, dim3(2304), dim3(256), 0, stream, w_out, wT);

  hipLaunchKernelGGL(k_gemm_qkv, dim3(9 * 1136), dim3(512), 0, stream,
                     features, Wbf, b_qkv, qkv);
  hipLaunchKernelGGL(k_attn, dim3(B_ * H_), dim3(256), 0, stream, qkv, mt, mi);
  hipLaunchKernelGGL(k_final, dim3(B_ / GFIN), dim3(256), 0, stream, mt, mi, wT, b_out, out);
}

// Round 14
// 961.891 us; speedup vs baseline: 1.3792x; 1.1148x over previous
//
#include <hip/hip_runtime.h>
#include <hip/hip_bf16.h>

#define B_ 2048
#define S_ 71
#define D_ 768
#define H_ 4
#define DH_ 192
#define TD_ 2304            // 3*D
#define M_ (B_ * S_)        // 145408 = 1136*128
#define TEXT_ 35
#define NKT 12              // 768 / 64 K-tiles

typedef unsigned short u16;
typedef unsigned int u32;
typedef __attribute__((ext_vector_type(4))) float f32x4;
typedef __attribute__((ext_vector_type(8))) short bf16x8;

__device__ __forceinline__ u16 f2bf(float f) {
  u32 u = __float_as_uint(f);
  u32 r = (u + 0x7FFFu + ((u >> 16) & 1u)) >> 16;  // RNE
  return (u16)r;
}
__device__ __forceinline__ float bf2f(u16 x) {
  return __uint_as_float(((u32)x) << 16);
}
// packed fp32->bf16 RNE via COMPILER intrinsic (round 11: inline-asm spills)
__device__ __forceinline__ u32 pk2bf(float lo, float hi) {
  __hip_bfloat162 h = __float22bfloat162_rn(float2{lo, hi});
  return *reinterpret_cast<u32*>(&h);
}

typedef __attribute__((address_space(1))) const unsigned int GASU;
typedef __attribute__((address_space(3))) unsigned int LASU;
__device__ __forceinline__ void gload16(const void* g, void* l) {
  __builtin_amdgcn_global_load_lds((GASU*)g, (LASU*)l, 16, 0, 0);
}

#define PHASE_BAR() do { __builtin_amdgcn_s_barrier(); asm volatile("" ::: "memory"); } while (0)
#define LGKM0() do { asm volatile("s_waitcnt lgkmcnt(0)" ::: "memory"); __builtin_amdgcn_sched_barrier(0); } while (0)

// ---------------------------------------------------------------------------
// fp32 -> bf16 elementwise (w_qkv, w_out)
__global__ __launch_bounds__(256) void k_cvt_bf16(const float* __restrict__ in,
                                                  u16* __restrict__ out, int n8) {
  int idx = blockIdx.x * 256 + threadIdx.x;
  if (idx >= n8) return;
  const float4* p = (const float4*)(in + (size_t)idx * 8);
  float4 a = p[0], b = p[1];
  uint4 o;
  o.x = pk2bf(a.x, a.y);
  o.y = pk2bf(a.z, a.w);
  o.z = pk2bf(b.x, b.y);
  o.w = pk2bf(b.z, b.w);
  *(uint4*)(out + (size_t)idx * 8) = o;
}

// ---------------------------------------------------------------------------
// Main GEMM (unchanged from round 13): C[M,2304] = A(fp32,cvt in-kernel) * Bw,
// bias + phi epilogue. 128x256, BK=64, A dbuf reg-staged, B gload_lds,
// 64KB LDS, 2 blocks/CU.
__global__ __launch_bounds__(512, 4) void k_gemm_qkv(
    const float* __restrict__ Afp,  // [M_,768] fp32 (features)
    const u16* __restrict__ Bw,     // [2304,768] bf16 (n-major)
    const float* __restrict__ bias, // [2304]
    u16* __restrict__ C)            // [M_,2304] bf16, phi on cols<1536
{
  __shared__ u16 sm[32768];   // 64 KiB
  int t = threadIdx.x;
  int lane = t & 63, wid = t >> 6;
  int wr = wid >> 2, wc = wid & 3;
  int lr = lane & 15;
  int g4 = lane >> 4;

  int swz = (blockIdx.x & 7) * 1278 + (blockIdx.x >> 3);
  int bm = swz / 9, bn = swz % 9;
  const size_t arow0 = (size_t)bm * 128;
  const int bcol0 = bn * 256;

  const float* srcAf[2];
  int dA[2];
#pragma unroll
  for (int j = 0; j < 2; ++j) {
    int c = j * 512 + t;
    srcAf[j] = Afp + (arow0 + (c >> 3)) * 768 + ((c & 7) ^ ((c >> 3) & 7)) * 8;
    dA[j] = c * 8;
  }
  const u16* srcB[4];
  int dB[4];
#pragma unroll
  for (int j = 0; j < 4; ++j) {
    int c = j * 512 + t;
    srcB[j] = Bw + (size_t)(bcol0 + (c >> 3)) * 768 + ((c & 7) ^ ((c >> 3) & 7)) * 8;
    dB[j] = 16384 + c * 8;
  }

#define STAGE_B(ktu) do { \
  gload16(srcB[0] + (ktu), &sm[dB[0]]); \
  gload16(srcB[1] + (ktu), &sm[dB[1]]); \
  gload16(srcB[2] + (ktu), &sm[dB[2]]); \
  gload16(srcB[3] + (ktu), &sm[dB[3]]); \
} while (0)
#define LOADA(ktu) do { \
  fa0 = *(const float4*)(srcAf[0] + (ktu)); \
  fa1 = *(const float4*)(srcAf[0] + (ktu) + 4); \
  fa2 = *(const float4*)(srcAf[1] + (ktu)); \
  fa3 = *(const float4*)(srcAf[1] + (ktu) + 4); \
} while (0)
#define WRITEA(abuf) do { \
  uint4 o0; \
  o0.x = pk2bf(fa0.x, fa0.y); o0.y = pk2bf(fa0.z, fa0.w); \
  o0.z = pk2bf(fa1.x, fa1.y); o0.w = pk2bf(fa1.z, fa1.w); \
  *(uint4*)(&sm[(abuf) + dA[0]]) = o0; \
  uint4 o1; \
  o1.x = pk2bf(fa2.x, fa2.y); o1.y = pk2bf(fa2.z, fa2.w); \
  o1.z = pk2bf(fa3.x, fa3.y); o1.w = pk2bf(fa3.z, fa3.w); \
  *(uint4*)(&sm[(abuf) + dA[1]]) = o1; \
} while (0)

  int gx0 = g4 ^ (lr & 7);
  int aro = (wr * 64 + lr) * 64;
  int bro = 16384 + (wc * 64 + lr) * 64;

  f32x4 acc[4][4] = {};
  float4 fa0, fa1, fa2, fa3;

  LOADA(0);
  STAGE_B(0);
  asm volatile("s_waitcnt vmcnt(0)" ::: "memory");
  WRITEA(0);
  asm volatile("s_waitcnt lgkmcnt(0)" ::: "memory");
  PHASE_BAR();

  int curA = 0;
  for (int T = 0; T < NKT; ++T) {
    int nxtA = 8192 - curA;
    bool pf = (T < NKT - 1);
    int ktu = (T + 1) * 64;
    bf16x8 b0[4], a0[4];
#pragma unroll
    for (int ni = 0; ni < 4; ++ni) b0[ni] = *(const bf16x8*)(&sm[bro + ni * 1024 + gx0 * 8]);
#pragma unroll
    for (int mi = 0; mi < 4; ++mi) a0[mi] = *(const bf16x8*)(&sm[curA + aro + mi * 1024 + gx0 * 8]);
    __builtin_amdgcn_s_setprio(1);
#pragma unroll
    for (int mi = 0; mi < 4; ++mi)
#pragma unroll
      for (int ni = 0; ni < 4; ++ni)
        acc[mi][ni] = __builtin_amdgcn_mfma_f32_16x16x32_bf16(a0[mi], b0[ni], acc[mi][ni], 0, 0, 0);
    __builtin_amdgcn_s_setprio(0);
    int gx1 = gx0 ^ 4;
    bf16x8 b1[4];
#pragma unroll
    for (int ni = 0; ni < 4; ++ni) b1[ni] = *(const bf16x8*)(&sm[bro + ni * 1024 + gx1 * 8]);
    LGKM0();
    PHASE_BAR();
    if (pf) { STAGE_B(ktu); LOADA(ktu); }
    bf16x8 a1[4];
#pragma unroll
    for (int mi = 0; mi < 4; ++mi) a1[mi] = *(const bf16x8*)(&sm[curA + aro + mi * 1024 + gx1 * 8]);
    __builtin_amdgcn_s_setprio(1);
#pragma unroll
    for (int mi = 0; mi < 4; ++mi)
#pragma unroll
      for (int ni = 0; ni < 4; ++ni)
        acc[mi][ni] = __builtin_amdgcn_mfma_f32_16x16x32_bf16(a1[mi], b1[ni], acc[mi][ni], 0, 0, 0);
    __builtin_amdgcn_s_setprio(0);
    if (pf) {
      asm volatile("s_waitcnt vmcnt(0)" ::: "memory");
      WRITEA(nxtA);
      asm volatile("s_waitcnt lgkmcnt(0)" ::: "memory");
      PHASE_BAR();
    }
    curA = nxtA;
  }

#pragma unroll
  for (int mi = 0; mi < 4; ++mi) {
#pragma unroll
    for (int ni = 0; ni < 4; ++ni) {
      int col = bcol0 + wc * 64 + ni * 16 + lr;
      float bb = bias[col];
#pragma unroll
      for (int i = 0; i < 4; ++i) {
        size_t row = arow0 + wr * 64 + mi * 16 + g4 * 4 + i;
        float v = acc[mi][ni][i] + bb;
        if (col < 1536) v = (v > 0.0f) ? (v + 1.0f) : __expf(v);
        C[row * TD_ + col] = f2bf(v);
      }
    }
  }
#undef STAGE_B
#undef LOADA
#undef WRITEA
}

// ---------------------------------------------------------------------------
// Attention core (round-13 structure); output G bf16 [4096][768]:
// row b = text-mean m_t, row 2048+b = image-mean m_i.
#define ALD 194

__global__ __launch_bounds__(256) void k_attn(
    const u16* __restrict__ qkv,  // [M_,2304] bf16
    u16* __restrict__ G)          // [4096,768] bf16
{
  __shared__ u16 qs[S_ * ALD];
  __shared__ u16 ks2[S_ * ALD];
  __shared__ float z[DH_], wt[S_], wi[S_], qt[DH_], qi[DH_], at[S_], ai[S_];
  int t = threadIdx.x;
  int b = blockIdx.x >> 2, h = blockIdx.x & 3;
  size_t base = (size_t)b * S_ * TD_;
  int qoff = h * DH_, koff = 768 + h * DH_, voff = 1536 + h * DH_;

  for (int idx = t; idx < S_ * 48; idx += 256) {
    int s = idx / 48, c = (idx % 48) * 4;
    *(ushort4*)(&qs[s * ALD + c])  = *(const ushort4*)(&qkv[base + (size_t)s * TD_ + qoff + c]);
    *(ushort4*)(&ks2[s * ALD + c]) = *(const ushort4*)(&qkv[base + (size_t)s * TD_ + koff + c]);
  }
  __syncthreads();
  if (t < DH_) {
    float a = 0;
    for (int s = 0; s < S_; ++s) a += bf2f(ks2[s * ALD + t]);
    z[t] = a;
  }
  __syncthreads();
  int grp = t >> 4, gl = t & 15;
  for (int s = grp; s < S_; s += 16) {
    float a = 0;
    int d0 = gl * 12;
#pragma unroll
    for (int i = 0; i < 12; ++i) a += bf2f(qs[s * ALD + d0 + i]) * z[d0 + i];
#pragma unroll
    for (int o = 8; o >= 1; o >>= 1) a += __shfl_xor(a, o);
    if (gl == 0) {
      float den = a + 1e-6f;
      wt[s] = (s < TEXT_) ? 1.0f / (35.0f * den) : 0.0f;
      wi[s] = (s >= TEXT_) ? 1.0f / (36.0f * den) : 0.0f;
    }
  }
  __syncthreads();
  if (t < DH_) {
    float aT = 0, aI = 0;
    for (int s = 0; s < S_; ++s) {
      float qv = bf2f(qs[s * ALD + t]);
      aT += qv * wt[s]; aI += qv * wi[s];
    }
    qt[t] = aT; qi[t] = aI;
  }
  __syncthreads();
  for (int s = grp; s < S_; s += 16) {
    float aT = 0, aI = 0;
    int d0 = gl * 12;
#pragma unroll
    for (int i = 0; i < 12; ++i) {
      float kv = bf2f(ks2[s * ALD + d0 + i]);
      aT += kv * qt[d0 + i]; aI += kv * qi[d0 + i];
    }
#pragma unroll
    for (int o = 8; o >= 1; o >>= 1) { aT += __shfl_xor(aT, o); aI += __shfl_xor(aI, o); }
    if (gl == 0) { at[s] = aT; ai[s] = aI; }
  }
  __syncthreads();
  if (t < DH_) {
    float aT = 0, aI = 0;
    for (int s = 0; s < S_; ++s) {
      float vv = bf2f(qkv[base + (size_t)s * TD_ + voff + t]);
      aT += at[s] * vv; aI += ai[s] * vv;
    }
    G[(size_t)b * 768 + qoff + t]          = f2bf(aT);
    G[(size_t)(2048 + b) * 768 + qoff + t] = f2bf(aI);
  }
}

// ---------------------------------------------------------------------------
// Head GEMM (round-9 structure, both operands bf16 via gload_lds):
// F[4096][768] = tanh(G * w_out^T + b_out), bf16 out. w_out [e][d] is
// consumed n-major AS-IS (no transpose). 128x256 tile, 96 blocks.
__global__ __launch_bounds__(512, 4) void k_gemm_head(
    const u16* __restrict__ Gb,   // [4096,768] bf16
    const u16* __restrict__ Wo,   // [768,768] bf16 (n-major: [e][d])
    const float* __restrict__ bout, // [768]
    u16* __restrict__ F)            // [4096,768] bf16
{
  __shared__ u16 sm[32768];
  int t = threadIdx.x;
  int lane = t & 63, wid = t >> 6;
  int wr = wid >> 2, wc = wid & 3;
  int lr = lane & 15;
  int g4 = lane >> 4;

  int bm = blockIdx.x / 3, bn = blockIdx.x % 3;
  const size_t arow0 = (size_t)bm * 128;
  const int bcol0 = bn * 256;

  const u16* srcA[2];
  int dA[2];
#pragma unroll
  for (int j = 0; j < 2; ++j) {
    int c = j * 512 + t;
    srcA[j] = Gb + (arow0 + (c >> 3)) * 768 + ((c & 7) ^ ((c >> 3) & 7)) * 8;
    dA[j] = c * 8;
  }
  const u16* srcB[4];
  int dB[4];
#pragma unroll
  for (int j = 0; j < 4; ++j) {
    int c = j * 512 + t;
    srcB[j] = Wo + (size_t)(bcol0 + (c >> 3)) * 768 + ((c & 7) ^ ((c >> 3) & 7)) * 8;
    dB[j] = 16384 + c * 8;
  }

#define STAGE_A2(abuf, ktu) do { \
  gload16(srcA[0] + (ktu), &sm[(abuf) + dA[0]]); \
  gload16(srcA[1] + (ktu), &sm[(abuf) + dA[1]]); \
} while (0)
#define STAGE_B2(ktu) do { \
  gload16(srcB[0] + (ktu), &sm[dB[0]]); \
  gload16(srcB[1] + (ktu), &sm[dB[1]]); \
  gload16(srcB[2] + (ktu), &sm[dB[2]]); \
  gload16(srcB[3] + (ktu), &sm[dB[3]]); \
} while (0)

  int gx0 = g4 ^ (lr & 7);
  int aro = (wr * 64 + lr) * 64;
  int bro = 16384 + (wc * 64 + lr) * 64;

  f32x4 acc[4][4] = {};

  STAGE_A2(0, 0); STAGE_B2(0);
  asm volatile("s_waitcnt vmcnt(0)" ::: "memory");
  PHASE_BAR();

  int curA = 0;
  for (int T = 0; T < NKT; ++T) {
    int nxtA = 8192 - curA;
    bool pf = (T < NKT - 1);
    int ktu = (T + 1) * 64;
    bf16x8 bfr[4][2];
#pragma unroll
    for (int ni = 0; ni < 4; ++ni) {
      bfr[ni][0] = *(const bf16x8*)(&sm[bro + ni * 1024 + gx0 * 8]);
      bfr[ni][1] = *(const bf16x8*)(&sm[bro + ni * 1024 + (gx0 ^ 4) * 8]);
    }
    LGKM0();
    PHASE_BAR();
    if (pf) { STAGE_B2(ktu); STAGE_A2(nxtA, ktu); }
    __builtin_amdgcn_s_setprio(1);
#pragma unroll
    for (int kk = 0; kk < 2; ++kk) {
      int gx = gx0 ^ (kk * 4);
      bf16x8 afr[4];
#pragma unroll
      for (int mi = 0; mi < 4; ++mi)
        afr[mi] = *(const bf16x8*)(&sm[curA + aro + mi * 1024 + gx * 8]);
#pragma unroll
      for (int mi = 0; mi < 4; ++mi)
#pragma unroll
        for (int ni = 0; ni < 4; ++ni)
          acc[mi][ni] = __builtin_amdgcn_mfma_f32_16x16x32_bf16(afr[mi], bfr[ni][kk], acc[mi][ni], 0, 0, 0);
    }
    __builtin_amdgcn_s_setprio(0);
    if (pf) {
      asm volatile("s_waitcnt vmcnt(0)" ::: "memory");
      PHASE_BAR();
    }
    curA = nxtA;
  }

#pragma unroll
  for (int mi = 0; mi < 4; ++mi) {
#pragma unroll
    for (int ni = 0; ni < 4; ++ni) {
      int col = bcol0 + wc * 64 + ni * 16 + lr;
      float bb = bout[col];
#pragma unroll
      for (int i = 0; i < 4; ++i) {
        size_t row = arow0 + wr * 64 + mi * 16 + g4 * 4 + i;
        F[row * 768 + col] = f2bf(tanhf(acc[mi][ni][i] + bb));
      }
    }
  }
#undef STAGE_A2
#undef STAGE_B2
}

// ---------------------------------------------------------------------------
// Cosine head: per b, read F rows b (r_t) and 2048+b (r_i), reduce.
#define GC 4
__global__ __launch_bounds__(256) void k_cos(
    const u16* __restrict__ F,    // [4096,768] bf16 (tanh already applied)
    float* __restrict__ out)      // [B_]
{
  __shared__ float red[3][4];
  int t = threadIdx.x, b0 = blockIdx.x * GC;
  int lane = t & 63, wid = t >> 6;
  for (int g = 0; g < GC; ++g) {
    int b = b0 + g;
    float st = 0, si = 0, sd = 0;
#pragma unroll
    for (int j = 0; j < 3; ++j) {
      int c = t + j * 256;
      float rt = bf2f(F[(size_t)b * 768 + c]);
      float ri = bf2f(F[(size_t)(2048 + b) * 768 + c]);
      st += rt * rt; si += ri * ri; sd += rt * ri;
    }
#pragma unroll
    for (int off = 32; off >= 1; off >>= 1) {
      st += __shfl_down(st, off);
      si += __shfl_down(si, off);
      sd += __shfl_down(sd, off);
    }
    __syncthreads();
    if (lane == 0) { red[0][wid] = st; red[1][wid] = si; red[2][wid] = sd; }
    __syncthreads();
    if (t == 0) {
      float S1 = red[0][0] + red[0][1] + red[0][2] + red[0][3];
      float S2 = red[1][0] + red[1][1] + red[1][2] + red[1][3];
      float S3 = red[2][0] + red[2][1] + red[2][2] + red[2][3];
      out[b] = S3 / (fmaxf(sqrtf(S1), 1e-8f) * fmaxf(sqrtf(S2), 1e-8f));
    }
  }
}

// ---------------------------------------------------------------------------
extern "C" void kernel_launch(void* const* d_in, const int* in_sizes, int n_in,
                              void* d_out, int out_size, void* d_ws, size_t ws_size,
                              hipStream_t stream) {
  const float* features = (const float*)d_in[0];
  // d_in[1] = attention_mask (unused by forward)
  const float* w_qkv = (const float*)d_in[2];
  const float* b_qkv = (const float*)d_in[3];
  const float* w_out = (const float*)d_in[4];
  const float* b_out = (const float*)d_in[5];
  float* out = (float*)d_out;

  char* ws = (char*)d_ws;
  size_t off = 0;
  auto alloc = [&](size_t bytes) {
    void* p = ws + off;
    off += (bytes + 255) & ~(size_t)255;
    return p;
  };
  u16* qkv  = (u16*)alloc((size_t)M_ * TD_ * 2);    // 670 MB
  u16* Wbf  = (u16*)alloc((size_t)TD_ * D_ * 2);    // 3.5 MB
  u16* Wobf = (u16*)alloc((size_t)D_ * D_ * 2);     // 1.2 MB
  u16* G    = (u16*)alloc((size_t)4096 * D_ * 2);   // 6.3 MB
  u16* F    = (u16*)alloc((size_t)4096 * D_ * 2);   // 6.3 MB
  (void)ws_size;

  hipLaunchKernelGGL(k_cvt_bf16, dim3((TD_ * D_ / 8 + 255) / 256), dim3(256), 0, stream,
                     w_qkv, Wbf, TD_ * D_ / 8);
  hipLaunchKernelGGL(k_cvt_bf16, dim3((D_ * D_ / 8 + 255) / 256), dim3(256), 0, stream,
                     w_out, Wobf, D_ * D_ / 8);

  hipLaunchKernelGGL(k_gemm_qkv, dim3(9 * 1136), dim3(512), 0, stream,
                     features, Wbf, b_qkv, qkv);
  hipLaunchKernelGGL(k_attn, dim3(B_ * H_), dim3(256), 0, stream, qkv, G);
  hipLaunchKernelGGL(k_gemm_head, dim3(32 * 3), dim3(512), 0, stream,
                     G, Wobf, b_out, F);
  hipLaunchKernelGGL(k_cos, dim3(B_ / GC), dim3(256), 0, stream, F, out);
}

// Round 15
// 858.731 us; speedup vs baseline: 1.5448x; 1.1201x over previous
//
#include <hip/hip_runtime.h>
#include <hip/hip_bf16.h>

#define B_ 2048
#define S_ 71
#define D_ 768
#define H_ 4
#define DH_ 192
#define TD2 1536            // q,k only
#define M_ (B_ * S_)        // 145408 = 1136*128
#define TEXT_ 35
#define NKT 12              // 768 / 64 K-tiles

typedef unsigned short u16;
typedef unsigned int u32;
typedef __attribute__((ext_vector_type(4))) float f32x4;
typedef __attribute__((ext_vector_type(8))) short bf16x8;

__device__ __forceinline__ u16 f2bf(float f) {
  u32 u = __float_as_uint(f);
  u32 r = (u + 0x7FFFu + ((u >> 16) & 1u)) >> 16;  // RNE
  return (u16)r;
}
__device__ __forceinline__ float bf2f(u16 x) {
  return __uint_as_float(((u32)x) << 16);
}
__device__ __forceinline__ u32 pk2bf(float lo, float hi) {
  __hip_bfloat162 h = __float22bfloat162_rn(float2{lo, hi});
  return *reinterpret_cast<u32*>(&h);
}

typedef __attribute__((address_space(1))) const unsigned int GASU;
typedef __attribute__((address_space(3))) unsigned int LASU;
__device__ __forceinline__ void gload16(const void* g, void* l) {
  __builtin_amdgcn_global_load_lds((GASU*)g, (LASU*)l, 16, 0, 0);
}

#define PHASE_BAR() do { __builtin_amdgcn_s_barrier(); asm volatile("" ::: "memory"); } while (0)
#define LGKM0() do { asm volatile("s_waitcnt lgkmcnt(0)" ::: "memory"); __builtin_amdgcn_sched_barrier(0); } while (0)

// ---------------------------------------------------------------------------
__global__ __launch_bounds__(256) void k_cvt_bf16(const float* __restrict__ in,
                                                  u16* __restrict__ out, int n8) {
  int idx = blockIdx.x * 256 + threadIdx.x;
  if (idx >= n8) return;
  const float4* p = (const float4*)(in + (size_t)idx * 8);
  float4 a = p[0], b = p[1];
  uint4 o;
  o.x = pk2bf(a.x, a.y);
  o.y = pk2bf(a.z, a.w);
  o.z = pk2bf(b.x, b.y);
  o.w = pk2bf(b.z, b.w);
  *(uint4*)(out + (size_t)idx * 8) = o;
}

// ---------------------------------------------------------------------------
// Main GEMM — q,k ONLY (v eliminated algebraically): C[M,1536] =
// phi(A(fp32) * Wqk^T + bias). Structure = round-13 (128x256, BK=64,
// A reg-staged dbuf, B gload_lds, 64KB LDS, 2 blocks/CU).
__global__ __launch_bounds__(512, 4) void k_gemm_qkv(
    const float* __restrict__ Afp,  // [M_,768] fp32 (features)
    const u16* __restrict__ Bw,     // [2304,768] bf16 (rows 0..1535 used)
    const float* __restrict__ bias, // [2304]
    u16* __restrict__ C)            // [M_,1536] bf16, phi everywhere
{
  __shared__ u16 sm[32768];   // 64 KiB
  int t = threadIdx.x;
  int lane = t & 63, wid = t >> 6;
  int wr = wid >> 2, wc = wid & 3;
  int lr = lane & 15;
  int g4 = lane >> 4;

  // XCD-bijective swizzle: nwg = 6816 = 8*852
  int swz = (blockIdx.x & 7) * 852 + (blockIdx.x >> 3);
  int bm = swz / 6, bn = swz % 6;
  const size_t arow0 = (size_t)bm * 128;
  const int bcol0 = bn * 256;

  const float* srcAf[2];
  int dA[2];
#pragma unroll
  for (int j = 0; j < 2; ++j) {
    int c = j * 512 + t;
    srcAf[j] = Afp + (arow0 + (c >> 3)) * 768 + ((c & 7) ^ ((c >> 3) & 7)) * 8;
    dA[j] = c * 8;
  }
  const u16* srcB[4];
  int dB[4];
#pragma unroll
  for (int j = 0; j < 4; ++j) {
    int c = j * 512 + t;
    srcB[j] = Bw + (size_t)(bcol0 + (c >> 3)) * 768 + ((c & 7) ^ ((c >> 3) & 7)) * 8;
    dB[j] = 16384 + c * 8;
  }

#define STAGE_B(ktu) do { \
  gload16(srcB[0] + (ktu), &sm[dB[0]]); \
  gload16(srcB[1] + (ktu), &sm[dB[1]]); \
  gload16(srcB[2] + (ktu), &sm[dB[2]]); \
  gload16(srcB[3] + (ktu), &sm[dB[3]]); \
} while (0)
#define LOADA(ktu) do { \
  fa0 = *(const float4*)(srcAf[0] + (ktu)); \
  fa1 = *(const float4*)(srcAf[0] + (ktu) + 4); \
  fa2 = *(const float4*)(srcAf[1] + (ktu)); \
  fa3 = *(const float4*)(srcAf[1] + (ktu) + 4); \
} while (0)
#define WRITEA(abuf) do { \
  uint4 o0; \
  o0.x = pk2bf(fa0.x, fa0.y); o0.y = pk2bf(fa0.z, fa0.w); \
  o0.z = pk2bf(fa1.x, fa1.y); o0.w = pk2bf(fa1.z, fa1.w); \
  *(uint4*)(&sm[(abuf) + dA[0]]) = o0; \
  uint4 o1; \
  o1.x = pk2bf(fa2.x, fa2.y); o1.y = pk2bf(fa2.z, fa2.w); \
  o1.z = pk2bf(fa3.x, fa3.y); o1.w = pk2bf(fa3.z, fa3.w); \
  *(uint4*)(&sm[(abuf) + dA[1]]) = o1; \
} while (0)

  int gx0 = g4 ^ (lr & 7);
  int aro = (wr * 64 + lr) * 64;
  int bro = 16384 + (wc * 64 + lr) * 64;

  f32x4 acc[4][4] = {};
  float4 fa0, fa1, fa2, fa3;

  LOADA(0);
  STAGE_B(0);
  asm volatile("s_waitcnt vmcnt(0)" ::: "memory");
  WRITEA(0);
  asm volatile("s_waitcnt lgkmcnt(0)" ::: "memory");
  PHASE_BAR();

  int curA = 0;
  for (int T = 0; T < NKT; ++T) {
    int nxtA = 8192 - curA;
    bool pf = (T < NKT - 1);
    int ktu = (T + 1) * 64;
    bf16x8 b0[4], a0[4];
#pragma unroll
    for (int ni = 0; ni < 4; ++ni) b0[ni] = *(const bf16x8*)(&sm[bro + ni * 1024 + gx0 * 8]);
#pragma unroll
    for (int mi = 0; mi < 4; ++mi) a0[mi] = *(const bf16x8*)(&sm[curA + aro + mi * 1024 + gx0 * 8]);
    __builtin_amdgcn_s_setprio(1);
#pragma unroll
    for (int mi = 0; mi < 4; ++mi)
#pragma unroll
      for (int ni = 0; ni < 4; ++ni)
        acc[mi][ni] = __builtin_amdgcn_mfma_f32_16x16x32_bf16(a0[mi], b0[ni], acc[mi][ni], 0, 0, 0);
    __builtin_amdgcn_s_setprio(0);
    int gx1 = gx0 ^ 4;
    bf16x8 b1[4];
#pragma unroll
    for (int ni = 0; ni < 4; ++ni) b1[ni] = *(const bf16x8*)(&sm[bro + ni * 1024 + gx1 * 8]);
    LGKM0();
    PHASE_BAR();
    if (pf) { STAGE_B(ktu); LOADA(ktu); }
    bf16x8 a1[4];
#pragma unroll
    for (int mi = 0; mi < 4; ++mi) a1[mi] = *(const bf16x8*)(&sm[curA + aro + mi * 1024 + gx1 * 8]);
    __builtin_amdgcn_s_setprio(1);
#pragma unroll
    for (int mi = 0; mi < 4; ++mi)
#pragma unroll
      for (int ni = 0; ni < 4; ++ni)
        acc[mi][ni] = __builtin_amdgcn_mfma_f32_16x16x32_bf16(a1[mi], b1[ni], acc[mi][ni], 0, 0, 0);
    __builtin_amdgcn_s_setprio(0);
    if (pf) {
      asm volatile("s_waitcnt vmcnt(0)" ::: "memory");
      WRITEA(nxtA);
      asm volatile("s_waitcnt lgkmcnt(0)" ::: "memory");
      PHASE_BAR();
    }
    curA = nxtA;
  }

#pragma unroll
  for (int mi = 0; mi < 4; ++mi) {
#pragma unroll
    for (int ni = 0; ni < 4; ++ni) {
      int col = bcol0 + wc * 64 + ni * 16 + lr;
      float bb = bias[col];
#pragma unroll
      for (int i = 0; i < 4; ++i) {
        size_t row = arow0 + wr * 64 + mi * 16 + g4 * 4 + i;
        float v = acc[mi][ni][i] + bb;
        v = (v > 0.0f) ? (v + 1.0f) : __expf(v);   // phi on everything (q,k)
        C[row * TD2 + col] = f2bf(v);
      }
    }
  }
#undef STAGE_B
#undef LOADA
#undef WRITEA
}

// ---------------------------------------------------------------------------
// Attention core v2 — one block per b; 4 heads sequential; never touches v.
// Produces Y[4096][3072] bf16 (row b = y_t, 2048+b = y_i; col h*768+d) and
// sat[4096][4] fp32 (sum of attention weights, for the v-bias term).
#define ALD 194

__global__ __launch_bounds__(256) void k_attn2(
    const u16* __restrict__ qk,   // [M_,1536] bf16 (phi applied)
    const float* __restrict__ x,  // [B_,71,768] fp32
    u16* __restrict__ Y,          // [4096,3072] bf16
    float* __restrict__ sat)      // [4096,4] fp32
{
  __shared__ u16 qs[S_ * ALD];
  __shared__ u16 ks[S_ * ALD];
  __shared__ float z[DH_], qt[DH_], qi[DH_], wt[S_], wi[S_];
  __shared__ float at_s[4][S_ + 1], ai_s[4][S_ + 1];
  int t = threadIdx.x, b = blockIdx.x;
  size_t base = (size_t)b * S_ * TD2;
  int grp = t >> 4, gl = t & 15;

  for (int h = 0; h < 4; ++h) {
    int qoff = h * DH_, koff = 768 + h * DH_;
    __syncthreads();   // protect qs/ks reuse across heads
    for (int idx = t; idx < S_ * 48; idx += 256) {
      int s = idx / 48, c = (idx % 48) * 4;
      *(ushort4*)(&qs[s * ALD + c]) = *(const ushort4*)(&qk[base + (size_t)s * TD2 + qoff + c]);
      *(ushort4*)(&ks[s * ALD + c]) = *(const ushort4*)(&qk[base + (size_t)s * TD2 + koff + c]);
    }
    __syncthreads();
    if (t < DH_) {
      float a = 0;
      for (int s = 0; s < S_; ++s) a += bf2f(ks[s * ALD + t]);
      z[t] = a;
    }
    __syncthreads();
    for (int s = grp; s < S_; s += 16) {
      float a = 0;
      int d0 = gl * 12;
#pragma unroll
      for (int i = 0; i < 12; ++i) a += bf2f(qs[s * ALD + d0 + i]) * z[d0 + i];
#pragma unroll
      for (int o = 8; o >= 1; o >>= 1) a += __shfl_xor(a, o);
      if (gl == 0) {
        float den = a + 1e-6f;
        wt[s] = (s < TEXT_) ? 1.0f / (35.0f * den) : 0.0f;
        wi[s] = (s >= TEXT_) ? 1.0f / (36.0f * den) : 0.0f;
      }
    }
    __syncthreads();
    if (t < DH_) {
      float aT = 0, aI = 0;
      for (int s = 0; s < S_; ++s) {
        float qv = bf2f(qs[s * ALD + t]);
        aT += qv * wt[s]; aI += qv * wi[s];
      }
      qt[t] = aT; qi[t] = aI;
    }
    __syncthreads();
    for (int s = grp; s < S_; s += 16) {
      float aT = 0, aI = 0;
      int d0 = gl * 12;
#pragma unroll
      for (int i = 0; i < 12; ++i) {
        float kv = bf2f(ks[s * ALD + d0 + i]);
        aT += kv * qt[d0 + i]; aI += kv * qi[d0 + i];
      }
#pragma unroll
      for (int o = 8; o >= 1; o >>= 1) { aT += __shfl_xor(aT, o); aI += __shfl_xor(aI, o); }
      if (gl == 0) { at_s[h][s] = aT; ai_s[h][s] = aI; }
    }
    __syncthreads();
    // sat[h] = sum_s at[h][s]  (wave 0; 71 = 64 + 7)
    if (t < 64) {
      float vT = at_s[h][t] + ((t < 7) ? at_s[h][t + 64] : 0.0f);
      float vI = ai_s[h][t] + ((t < 7) ? ai_s[h][t + 64] : 0.0f);
#pragma unroll
      for (int o = 32; o >= 1; o >>= 1) { vT += __shfl_xor(vT, o); vI += __shfl_xor(vI, o); }
      if (t == 0) {
        sat[(size_t)b * 4 + h] = vT;
        sat[(size_t)(2048 + b) * 4 + h] = vI;
      }
    }
  }
  __syncthreads();
  // Phase B: stream x once, accumulate y for all 4 heads (t,i)
  float yt[4][3] = {}, yi[4][3] = {};
  const float* xb = x + (size_t)b * S_ * 768;
#pragma unroll 2
  for (int s = 0; s < S_; ++s) {
    float xv0 = xb[(size_t)s * 768 + t];
    float xv1 = xb[(size_t)s * 768 + t + 256];
    float xv2 = xb[(size_t)s * 768 + t + 512];
#pragma unroll
    for (int h = 0; h < 4; ++h) {
      float a = at_s[h][s], ai_ = ai_s[h][s];
      yt[h][0] += a * xv0; yt[h][1] += a * xv1; yt[h][2] += a * xv2;
      yi[h][0] += ai_ * xv0; yi[h][1] += ai_ * xv1; yi[h][2] += ai_ * xv2;
    }
  }
  size_t rt = (size_t)b * 3072, ri = (size_t)(2048 + b) * 3072;
#pragma unroll
  for (int h = 0; h < 4; ++h)
#pragma unroll
    for (int j = 0; j < 3; ++j) {
      Y[rt + h * 768 + t + j * 256] = f2bf(yt[h][j]);
      Y[ri + h * 768 + t + j * 256] = f2bf(yi[h][j]);
    }
}

// ---------------------------------------------------------------------------
// Grouped v-GEMM: G[4096][768] = Y_h * Wv_h^T + sat*bv (per head h).
// 128x64 tile, BK=64, 4 waves (2Mx2N, wave 64x32), dbuf A+B, 48 KB LDS.
// grid: bm(32) x nt(12); head = nt/3.
__global__ __launch_bounds__(256, 4) void k_gemm_v(
    const u16* __restrict__ Yb,    // [4096,3072] bf16
    const u16* __restrict__ Wbf,   // [2304,768] bf16 (rows 1536+ = Wv)
    const float* __restrict__ bqkv,
    const float* __restrict__ sat, // [4096,4]
    u16* __restrict__ G)           // [4096,768] bf16
{
  // u16 units: A0 [0,8192) A1 [8192,16384) B0 [16384,20480) B1 [20480,24576)
  __shared__ u16 sm[24576];
  int t = threadIdx.x;
  int lane = t & 63, wid = t >> 6;
  int wr = wid >> 1, wc = wid & 1;
  int lr = lane & 15, g4 = lane >> 4;
  int bm = blockIdx.x / 12, nt = blockIdx.x % 12;
  int h = nt / 3, e0 = (nt % 3) * 64;
  const size_t arow0 = (size_t)bm * 128;

  const u16* srcA[4];
  int dA[4];
#pragma unroll
  for (int j = 0; j < 4; ++j) {
    int c = j * 256 + t;
    int row = c >> 3, kg = (c & 7) ^ (row & 7);
    srcA[j] = Yb + (arow0 + row) * 3072 + h * 768 + kg * 8;
    dA[j] = c * 8;
  }
  const u16* srcB[2];
  int dB[2];
#pragma unroll
  for (int j = 0; j < 2; ++j) {
    int c = j * 256 + t;
    int row = c >> 3, kg = (c & 7) ^ (row & 7);
    srcB[j] = Wbf + (size_t)(1536 + h * DH_ + e0 + row) * 768 + kg * 8;
    dB[j] = c * 8;
  }

#define VSTAGE(abuf, bbuf, ktu) do { \
  gload16(srcA[0] + (ktu), &sm[(abuf) + dA[0]]); \
  gload16(srcA[1] + (ktu), &sm[(abuf) + dA[1]]); \
  gload16(srcA[2] + (ktu), &sm[(abuf) + dA[2]]); \
  gload16(srcA[3] + (ktu), &sm[(abuf) + dA[3]]); \
  gload16(srcB[0] + (ktu), &sm[(bbuf) + dB[0]]); \
  gload16(srcB[1] + (ktu), &sm[(bbuf) + dB[1]]); \
} while (0)

  int gx0 = g4 ^ (lr & 7);
  int aro = (wr * 64 + lr) * 64;          // + mi*1024 + gx*8 (rel abuf)
  int bro = (wc * 32 + lr) * 64;          // + ni*1024 (rel bbuf)

  f32x4 acc[4][2] = {};

  VSTAGE(0, 16384, 0);
  asm volatile("s_waitcnt vmcnt(0)" ::: "memory");
  PHASE_BAR();

  for (int T = 0; T < NKT; ++T) {
    int abuf = (T & 1) * 8192, bbuf = 16384 + (T & 1) * 4096;
    bool pf = (T < NKT - 1);
    if (pf) VSTAGE(8192 - abuf, 16384 + 4096 - (bbuf - 16384), (T + 1) * 64);
#pragma unroll
    for (int kk = 0; kk < 2; ++kk) {
      int gx = gx0 ^ (kk * 4);
      bf16x8 a[4], bfr[2];
#pragma unroll
      for (int mi = 0; mi < 4; ++mi) a[mi] = *(const bf16x8*)(&sm[abuf + aro + mi * 1024 + gx * 8]);
#pragma unroll
      for (int ni = 0; ni < 2; ++ni) bfr[ni] = *(const bf16x8*)(&sm[bbuf + bro + ni * 1024 + gx * 8]);
#pragma unroll
      for (int mi = 0; mi < 4; ++mi)
#pragma unroll
        for (int ni = 0; ni < 2; ++ni)
          acc[mi][ni] = __builtin_amdgcn_mfma_f32_16x16x32_bf16(a[mi], bfr[ni], acc[mi][ni], 0, 0, 0);
    }
    if (pf) {
      asm volatile("s_waitcnt vmcnt(0)" ::: "memory");
      PHASE_BAR();
    }
  }

#pragma unroll
  for (int mi = 0; mi < 4; ++mi) {
#pragma unroll
    for (int ni = 0; ni < 2; ++ni) {
      int e = e0 + wc * 32 + ni * 16 + lr;
      int gcol = h * DH_ + e;
      float bv = bqkv[1536 + gcol];
#pragma unroll
      for (int i = 0; i < 4; ++i) {
        size_t row = arow0 + wr * 64 + mi * 16 + g4 * 4 + i;
        G[row * 768 + gcol] = f2bf(acc[mi][ni][i] + sat[row * 4 + h] * bv);
      }
    }
  }
#undef VSTAGE
}

// ---------------------------------------------------------------------------
// Head GEMM (unchanged, verified): F = tanh(G * w_out^T + b_out)
__global__ __launch_bounds__(512, 4) void k_gemm_head(
    const u16* __restrict__ Gb,   // [4096,768] bf16
    const u16* __restrict__ Wo,   // [768,768] bf16 (n-major)
    const float* __restrict__ bout,
    u16* __restrict__ F)          // [4096,768] bf16
{
  __shared__ u16 sm[32768];
  int t = threadIdx.x;
  int lane = t & 63, wid = t >> 6;
  int wr = wid >> 2, wc = wid & 3;
  int lr = lane & 15;
  int g4 = lane >> 4;

  int bm = blockIdx.x / 3, bn = blockIdx.x % 3;
  const size_t arow0 = (size_t)bm * 128;
  const int bcol0 = bn * 256;

  const u16* srcA[2];
  int dA[2];
#pragma unroll
  for (int j = 0; j < 2; ++j) {
    int c = j * 512 + t;
    srcA[j] = Gb + (arow0 + (c >> 3)) * 768 + ((c & 7) ^ ((c >> 3) & 7)) * 8;
    dA[j] = c * 8;
  }
  const u16* srcB[4];
  int dB[4];
#pragma unroll
  for (int j = 0; j < 4; ++j) {
    int c = j * 512 + t;
    srcB[j] = Wo + (size_t)(bcol0 + (c >> 3)) * 768 + ((c & 7) ^ ((c >> 3) & 7)) * 8;
    dB[j] = 16384 + c * 8;
  }

#define STAGE_A2(abuf, ktu) do { \
  gload16(srcA[0] + (ktu), &sm[(abuf) + dA[0]]); \
  gload16(srcA[1] + (ktu), &sm[(abuf) + dA[1]]); \
} while (0)
#define STAGE_B2(ktu) do { \
  gload16(srcB[0] + (ktu), &sm[dB[0]]); \
  gload16(srcB[1] + (ktu), &sm[dB[1]]); \
  gload16(srcB[2] + (ktu), &sm[dB[2]]); \
  gload16(srcB[3] + (ktu), &sm[dB[3]]); \
} while (0)

  int gx0 = g4 ^ (lr & 7);
  int aro = (wr * 64 + lr) * 64;
  int bro = 16384 + (wc * 64 + lr) * 64;

  f32x4 acc[4][4] = {};

  STAGE_A2(0, 0); STAGE_B2(0);
  asm volatile("s_waitcnt vmcnt(0)" ::: "memory");
  PHASE_BAR();

  int curA = 0;
  for (int T = 0; T < NKT; ++T) {
    int nxtA = 8192 - curA;
    bool pf = (T < NKT - 1);
    int ktu = (T + 1) * 64;
    bf16x8 bfr[4][2];
#pragma unroll
    for (int ni = 0; ni < 4; ++ni) {
      bfr[ni][0] = *(const bf16x8*)(&sm[bro + ni * 1024 + gx0 * 8]);
      bfr[ni][1] = *(const bf16x8*)(&sm[bro + ni * 1024 + (gx0 ^ 4) * 8]);
    }
    LGKM0();
    PHASE_BAR();
    if (pf) { STAGE_B2(ktu); STAGE_A2(nxtA, ktu); }
    __builtin_amdgcn_s_setprio(1);
#pragma unroll
    for (int kk = 0; kk < 2; ++kk) {
      int gx = gx0 ^ (kk * 4);
      bf16x8 afr[4];
#pragma unroll
      for (int mi = 0; mi < 4; ++mi)
        afr[mi] = *(const bf16x8*)(&sm[curA + aro + mi * 1024 + gx * 8]);
#pragma unroll
      for (int mi = 0; mi < 4; ++mi)
#pragma unroll
        for (int ni = 0; ni < 4; ++ni)
          acc[mi][ni] = __builtin_amdgcn_mfma_f32_16x16x32_bf16(afr[mi], bfr[ni][kk], acc[mi][ni], 0, 0, 0);
    }
    __builtin_amdgcn_s_setprio(0);
    if (pf) {
      asm volatile("s_waitcnt vmcnt(0)" ::: "memory");
      PHASE_BAR();
    }
    curA = nxtA;
  }

#pragma unroll
  for (int mi = 0; mi < 4; ++mi) {
#pragma unroll
    for (int ni = 0; ni < 4; ++ni) {
      int col = bcol0 + wc * 64 + ni * 16 + lr;
      float bb = bout[col];
#pragma unroll
      for (int i = 0; i < 4; ++i) {
        size_t row = arow0 + wr * 64 + mi * 16 + g4 * 4 + i;
        F[row * 768 + col] = f2bf(tanhf(acc[mi][ni][i] + bb));
      }
    }
  }
#undef STAGE_A2
#undef STAGE_B2
}

// ---------------------------------------------------------------------------
#define GC 4
__global__ __launch_bounds__(256) void k_cos(
    const u16* __restrict__ F,    // [4096,768] bf16 (tanh applied)
    float* __restrict__ out)      // [B_]
{
  __shared__ float red[3][4];
  int t = threadIdx.x, b0 = blockIdx.x * GC;
  int lane = t & 63, wid = t >> 6;
  for (int g = 0; g < GC; ++g) {
    int b = b0 + g;
    float st = 0, si = 0, sd = 0;
#pragma unroll
    for (int j = 0; j < 3; ++j) {
      int c = t + j * 256;
      float rt = bf2f(F[(size_t)b * 768 + c]);
      float ri = bf2f(F[(size_t)(2048 + b) * 768 + c]);
      st += rt * rt; si += ri * ri; sd += rt * ri;
    }
#pragma unroll
    for (int off = 32; off >= 1; off >>= 1) {
      st += __shfl_down(st, off);
      si += __shfl_down(si, off);
      sd += __shfl_down(sd, off);
    }
    __syncthreads();
    if (lane == 0) { red[0][wid] = st; red[1][wid] = si; red[2][wid] = sd; }
    __syncthreads();
    if (t == 0) {
      float S1 = red[0][0] + red[0][1] + red[0][2] + red[0][3];
      float S2 = red[1][0] + red[1][1] + red[1][2] + red[1][3];
      float S3 = red[2][0] + red[2][1] + red[2][2] + red[2][3];
      out[b] = S3 / (fmaxf(sqrtf(S1), 1e-8f) * fmaxf(sqrtf(S2), 1e-8f));
    }
  }
}

// ---------------------------------------------------------------------------
extern "C" void kernel_launch(void* const* d_in, const int* in_sizes, int n_in,
                              void* d_out, int out_size, void* d_ws, size_t ws_size,
                              hipStream_t stream) {
  const float* features = (const float*)d_in[0];
  // d_in[1] = attention_mask (unused by forward)
  const float* w_qkv = (const float*)d_in[2];
  const float* b_qkv = (const float*)d_in[3];
  const float* w_out = (const float*)d_in[4];
  const float* b_out = (const float*)d_in[5];
  float* out = (float*)d_out;

  char* ws = (char*)d_ws;
  size_t off = 0;
  auto alloc = [&](size_t bytes) {
    void* p = ws + off;
    off += (bytes + 255) & ~(size_t)255;
    return p;
  };
  u16* QK   = (u16*)alloc((size_t)M_ * TD2 * 2);     // 436 MB
  u16* Wbf  = (u16*)alloc((size_t)2304 * D_ * 2);    // 3.5 MB
  u16* Wobf = (u16*)alloc((size_t)D_ * D_ * 2);      // 1.2 MB
  u16* Yv   = (u16*)alloc((size_t)4096 * 3072 * 2);  // 25 MB
  float* sat = (float*)alloc((size_t)4096 * 4 * 4);  // 64 KB
  u16* G    = (u16*)alloc((size_t)4096 * D_ * 2);    // 6.3 MB
  u16* F    = (u16*)alloc((size_t)4096 * D_ * 2);    // 6.3 MB
  (void)ws_size;

  hipLaunchKernelGGL(k_cvt_bf16, dim3((2304 * D_ / 8 + 255) / 256), dim3(256), 0, stream,
                     w_qkv, Wbf, 2304 * D_ / 8);
  hipLaunchKernelGGL(k_cvt_bf16, dim3((D_ * D_ / 8 + 255) / 256), dim3(256), 0, stream,
                     w_out, Wobf, D_ * D_ / 8);

  hipLaunchKernelGGL(k_gemm_qkv, dim3(6 * 1136), dim3(512), 0, stream,
                     features, Wbf, b_qkv, QK);
  hipLaunchKernelGGL(k_attn2, dim3(B_), dim3(256), 0, stream, QK, features, Yv, sat);
  hipLaunchKernelGGL(k_gemm_v, dim3(32 * 12), dim3(256), 0, stream,
                     Yv, Wbf, b_qkv, sat, G);
  hipLaunchKernelGGL(k_gemm_head, dim3(32 * 3), dim3(512), 0, stream,
                     G, Wobf, b_out, F);
  hipLaunchKernelGGL(k_cos, dim3(B_ / GC), dim3(256), 0, stream, F, out);
}

// Round 16
// 803.548 us; speedup vs baseline: 1.6509x; 1.0687x over previous
//
#include <hip/hip_runtime.h>
#include <hip/hip_bf16.h>

#define B_ 2048
#define S_ 71
#define SP 72               // padded stride for at/ai
#define D_ 768
#define H_ 4
#define DH_ 192
#define TD2 1536            // q,k only
#define M_ (B_ * S_)        // 145408 = 1136*128
#define TEXT_ 35
#define NKT 12              // 768 / 64 K-tiles

typedef unsigned short u16;
typedef unsigned int u32;
typedef __attribute__((ext_vector_type(4))) float f32x4;
typedef __attribute__((ext_vector_type(8))) short bf16x8;

__device__ __forceinline__ u16 f2bf(float f) {
  u32 u = __float_as_uint(f);
  u32 r = (u + 0x7FFFu + ((u >> 16) & 1u)) >> 16;  // RNE
  return (u16)r;
}
__device__ __forceinline__ float bf2f(u16 x) {
  return __uint_as_float(((u32)x) << 16);
}
__device__ __forceinline__ u32 pk2bf(float lo, float hi) {
  __hip_bfloat162 h = __float22bfloat162_rn(float2{lo, hi});
  return *reinterpret_cast<u32*>(&h);
}

typedef __attribute__((address_space(1))) const unsigned int GASU;
typedef __attribute__((address_space(3))) unsigned int LASU;
__device__ __forceinline__ void gload16(const void* g, void* l) {
  __builtin_amdgcn_global_load_lds((GASU*)g, (LASU*)l, 16, 0, 0);
}

#define PHASE_BAR() do { __builtin_amdgcn_s_barrier(); asm volatile("" ::: "memory"); } while (0)
#define LGKM0() do { asm volatile("s_waitcnt lgkmcnt(0)" ::: "memory"); __builtin_amdgcn_sched_barrier(0); } while (0)

// ---------------------------------------------------------------------------
__global__ __launch_bounds__(256) void k_cvt_bf16(const float* __restrict__ in,
                                                  u16* __restrict__ out, int n8) {
  int idx = blockIdx.x * 256 + threadIdx.x;
  if (idx >= n8) return;
  const float4* p = (const float4*)(in + (size_t)idx * 8);
  float4 a = p[0], b = p[1];
  uint4 o;
  o.x = pk2bf(a.x, a.y);
  o.y = pk2bf(a.z, a.w);
  o.z = pk2bf(b.x, b.y);
  o.w = pk2bf(b.z, b.w);
  *(uint4*)(out + (size_t)idx * 8) = o;
}

// ---------------------------------------------------------------------------
// Main GEMM — q,k only: C[M,1536] = phi(A(fp32) * Wqk^T + bias).
// 128x256, BK=64, A reg-staged dbuf, B gload_lds, 64KB LDS, 2 blocks/CU.
__global__ __launch_bounds__(512, 4) void k_gemm_qkv(
    const float* __restrict__ Afp,  // [M_,768] fp32 (features)
    const u16* __restrict__ Bw,     // [2304,768] bf16 (rows 0..1535 used)
    const float* __restrict__ bias, // [2304]
    u16* __restrict__ C)            // [M_,1536] bf16, phi everywhere
{
  __shared__ u16 sm[32768];   // 64 KiB
  int t = threadIdx.x;
  int lane = t & 63, wid = t >> 6;
  int wr = wid >> 2, wc = wid & 3;
  int lr = lane & 15;
  int g4 = lane >> 4;

  // XCD-bijective swizzle: nwg = 6816 = 8*852
  int swz = (blockIdx.x & 7) * 852 + (blockIdx.x >> 3);
  int bm = swz / 6, bn = swz % 6;
  const size_t arow0 = (size_t)bm * 128;
  const int bcol0 = bn * 256;

  const float* srcAf[2];
  int dA[2];
#pragma unroll
  for (int j = 0; j < 2; ++j) {
    int c = j * 512 + t;
    srcAf[j] = Afp + (arow0 + (c >> 3)) * 768 + ((c & 7) ^ ((c >> 3) & 7)) * 8;
    dA[j] = c * 8;
  }
  const u16* srcB[4];
  int dB[4];
#pragma unroll
  for (int j = 0; j < 4; ++j) {
    int c = j * 512 + t;
    srcB[j] = Bw + (size_t)(bcol0 + (c >> 3)) * 768 + ((c & 7) ^ ((c >> 3) & 7)) * 8;
    dB[j] = 16384 + c * 8;
  }

#define STAGE_B(ktu) do { \
  gload16(srcB[0] + (ktu), &sm[dB[0]]); \
  gload16(srcB[1] + (ktu), &sm[dB[1]]); \
  gload16(srcB[2] + (ktu), &sm[dB[2]]); \
  gload16(srcB[3] + (ktu), &sm[dB[3]]); \
} while (0)
#define LOADA(ktu) do { \
  fa0 = *(const float4*)(srcAf[0] + (ktu)); \
  fa1 = *(const float4*)(srcAf[0] + (ktu) + 4); \
  fa2 = *(const float4*)(srcAf[1] + (ktu)); \
  fa3 = *(const float4*)(srcAf[1] + (ktu) + 4); \
} while (0)
#define WRITEA(abuf) do { \
  uint4 o0; \
  o0.x = pk2bf(fa0.x, fa0.y); o0.y = pk2bf(fa0.z, fa0.w); \
  o0.z = pk2bf(fa1.x, fa1.y); o0.w = pk2bf(fa1.z, fa1.w); \
  *(uint4*)(&sm[(abuf) + dA[0]]) = o0; \
  uint4 o1; \
  o1.x = pk2bf(fa2.x, fa2.y); o1.y = pk2bf(fa2.z, fa2.w); \
  o1.z = pk2bf(fa3.x, fa3.y); o1.w = pk2bf(fa3.z, fa3.w); \
  *(uint4*)(&sm[(abuf) + dA[1]]) = o1; \
} while (0)

  int gx0 = g4 ^ (lr & 7);
  int aro = (wr * 64 + lr) * 64;
  int bro = 16384 + (wc * 64 + lr) * 64;

  f32x4 acc[4][4] = {};
  float4 fa0, fa1, fa2, fa3;

  LOADA(0);
  STAGE_B(0);
  asm volatile("s_waitcnt vmcnt(0)" ::: "memory");
  WRITEA(0);
  asm volatile("s_waitcnt lgkmcnt(0)" ::: "memory");
  PHASE_BAR();

  int curA = 0;
  for (int T = 0; T < NKT; ++T) {
    int nxtA = 8192 - curA;
    bool pf = (T < NKT - 1);
    int ktu = (T + 1) * 64;
    bf16x8 b0[4], a0[4];
#pragma unroll
    for (int ni = 0; ni < 4; ++ni) b0[ni] = *(const bf16x8*)(&sm[bro + ni * 1024 + gx0 * 8]);
#pragma unroll
    for (int mi = 0; mi < 4; ++mi) a0[mi] = *(const bf16x8*)(&sm[curA + aro + mi * 1024 + gx0 * 8]);
    __builtin_amdgcn_s_setprio(1);
#pragma unroll
    for (int mi = 0; mi < 4; ++mi)
#pragma unroll
      for (int ni = 0; ni < 4; ++ni)
        acc[mi][ni] = __builtin_amdgcn_mfma_f32_16x16x32_bf16(a0[mi], b0[ni], acc[mi][ni], 0, 0, 0);
    __builtin_amdgcn_s_setprio(0);
    int gx1 = gx0 ^ 4;
    bf16x8 b1[4];
#pragma unroll
    for (int ni = 0; ni < 4; ++ni) b1[ni] = *(const bf16x8*)(&sm[bro + ni * 1024 + gx1 * 8]);
    LGKM0();
    PHASE_BAR();
    if (pf) { STAGE_B(ktu); LOADA(ktu); }
    bf16x8 a1[4];
#pragma unroll
    for (int mi = 0; mi < 4; ++mi) a1[mi] = *(const bf16x8*)(&sm[curA + aro + mi * 1024 + gx1 * 8]);
    __builtin_amdgcn_s_setprio(1);
#pragma unroll
    for (int mi = 0; mi < 4; ++mi)
#pragma unroll
      for (int ni = 0; ni < 4; ++ni)
        acc[mi][ni] = __builtin_amdgcn_mfma_f32_16x16x32_bf16(a1[mi], b1[ni], acc[mi][ni], 0, 0, 0);
    __builtin_amdgcn_s_setprio(0);
    if (pf) {
      asm volatile("s_waitcnt vmcnt(0)" ::: "memory");
      WRITEA(nxtA);
      asm volatile("s_waitcnt lgkmcnt(0)" ::: "memory");
      PHASE_BAR();
    }
    curA = nxtA;
  }

#pragma unroll
  for (int mi = 0; mi < 4; ++mi) {
#pragma unroll
    for (int ni = 0; ni < 4; ++ni) {
      int col = bcol0 + wc * 64 + ni * 16 + lr;
      float bb = bias[col];
#pragma unroll
      for (int i = 0; i < 4; ++i) {
        size_t row = arow0 + wr * 64 + mi * 16 + g4 * 4 + i;
        float v = acc[mi][ni][i] + bb;
        v = (v > 0.0f) ? (v + 1.0f) : __expf(v);   // phi (q,k)
        C[row * TD2 + col] = f2bf(v);
      }
    }
  }
#undef STAGE_B
#undef LOADA
#undef WRITEA
}

// ---------------------------------------------------------------------------
// Attention qk-phases: one block per (b,h) (8192 blocks). Computes the
// attention weights at/ai[b,h,s] and their sums sat. No v, no x.
#define ALD 194

__global__ __launch_bounds__(256) void k_attn_qk(
    const u16* __restrict__ qk,   // [M_,1536] bf16 (phi applied)
    float* __restrict__ AT,       // [B_,4,SP]
    float* __restrict__ AI,       // [B_,4,SP]
    float* __restrict__ sat)      // [4096,4]
{
  __shared__ u16 qs[S_ * ALD];
  __shared__ u16 ks[S_ * ALD];
  __shared__ float z[DH_], qt[DH_], qi[DH_], wt[S_], wi[S_];
  __shared__ float at_l[S_ + 1], ai_l[S_ + 1];
  int t = threadIdx.x;
  int b = blockIdx.x >> 2, h = blockIdx.x & 3;
  size_t base = (size_t)b * S_ * TD2;
  int qoff = h * DH_, koff = 768 + h * DH_;
  int grp = t >> 4, gl = t & 15;

  for (int idx = t; idx < S_ * 48; idx += 256) {
    int s = idx / 48, c = (idx % 48) * 4;
    *(ushort4*)(&qs[s * ALD + c]) = *(const ushort4*)(&qk[base + (size_t)s * TD2 + qoff + c]);
    *(ushort4*)(&ks[s * ALD + c]) = *(const ushort4*)(&qk[base + (size_t)s * TD2 + koff + c]);
  }
  __syncthreads();
  if (t < DH_) {
    float a = 0;
    for (int s = 0; s < S_; ++s) a += bf2f(ks[s * ALD + t]);
    z[t] = a;
  }
  __syncthreads();
  for (int s = grp; s < S_; s += 16) {
    float a = 0;
    int d0 = gl * 12;
#pragma unroll
    for (int i = 0; i < 12; ++i) a += bf2f(qs[s * ALD + d0 + i]) * z[d0 + i];
#pragma unroll
    for (int o = 8; o >= 1; o >>= 1) a += __shfl_xor(a, o);
    if (gl == 0) {
      float den = a + 1e-6f;
      wt[s] = (s < TEXT_) ? 1.0f / (35.0f * den) : 0.0f;
      wi[s] = (s >= TEXT_) ? 1.0f / (36.0f * den) : 0.0f;
    }
  }
  __syncthreads();
  if (t < DH_) {
    float aT = 0, aI = 0;
    for (int s = 0; s < S_; ++s) {
      float qv = bf2f(qs[s * ALD + t]);
      aT += qv * wt[s]; aI += qv * wi[s];
    }
    qt[t] = aT; qi[t] = aI;
  }
  __syncthreads();
  size_t arow = ((size_t)b * 4 + h) * SP;
  for (int s = grp; s < S_; s += 16) {
    float aT = 0, aI = 0;
    int d0 = gl * 12;
#pragma unroll
    for (int i = 0; i < 12; ++i) {
      float kv = bf2f(ks[s * ALD + d0 + i]);
      aT += kv * qt[d0 + i]; aI += kv * qi[d0 + i];
    }
#pragma unroll
    for (int o = 8; o >= 1; o >>= 1) { aT += __shfl_xor(aT, o); aI += __shfl_xor(aI, o); }
    if (gl == 0) {
      at_l[s] = aT; ai_l[s] = aI;
      AT[arow + s] = aT; AI[arow + s] = aI;
    }
  }
  __syncthreads();
  if (t < 64) {
    float vT = at_l[t < S_ ? t : 0] * (t < S_ ? 1.0f : 0.0f) + ((t < 7) ? at_l[t + 64] : 0.0f);
    float vI = ai_l[t < S_ ? t : 0] * (t < S_ ? 1.0f : 0.0f) + ((t < 7) ? ai_l[t + 64] : 0.0f);
#pragma unroll
    for (int o = 32; o >= 1; o >>= 1) { vT += __shfl_xor(vT, o); vI += __shfl_xor(vI, o); }
    if (t == 0) {
      sat[(size_t)b * 4 + h] = vT;
      sat[(size_t)(2048 + b) * 4 + h] = vI;
    }
  }
}

// ---------------------------------------------------------------------------
// Y accumulation: block per b, 192 threads; streams x once (float4),
// accumulates y_t/y_i for all 4 heads in registers. Pure-BW kernel.
__global__ __launch_bounds__(192) void k_accy(
    const float* __restrict__ x,  // [B_,71,768] fp32
    const float* __restrict__ AT, // [B_,4,SP]
    const float* __restrict__ AI,
    u16* __restrict__ Y)          // [4096,3072] bf16
{
  __shared__ float at_s[4][S_], ai_s[4][S_];
  int t = threadIdx.x, b = blockIdx.x;
  for (int i = t; i < 4 * S_; i += 192) {
    int h = i / S_, s = i % S_;
    at_s[h][s] = AT[((size_t)b * 4 + h) * SP + s];
    ai_s[h][s] = AI[((size_t)b * 4 + h) * SP + s];
  }
  __syncthreads();
  float4 yt[4] = {}, yi[4] = {};
  const float4* xb = (const float4*)(x + (size_t)b * S_ * 768);
  for (int s = 0; s < S_; ++s) {
    float4 xv = xb[s * 192 + t];
#pragma unroll
    for (int h = 0; h < 4; ++h) {
      float a = at_s[h][s], ai_ = ai_s[h][s];
      yt[h].x += a * xv.x; yt[h].y += a * xv.y; yt[h].z += a * xv.z; yt[h].w += a * xv.w;
      yi[h].x += ai_ * xv.x; yi[h].y += ai_ * xv.y; yi[h].z += ai_ * xv.z; yi[h].w += ai_ * xv.w;
    }
  }
  size_t rt = (size_t)b * 3072, ri = (size_t)(2048 + b) * 3072;
#pragma unroll
  for (int h = 0; h < 4; ++h) {
    uint2 ot, oi;
    ot.x = pk2bf(yt[h].x, yt[h].y); ot.y = pk2bf(yt[h].z, yt[h].w);
    oi.x = pk2bf(yi[h].x, yi[h].y); oi.y = pk2bf(yi[h].z, yi[h].w);
    *(uint2*)(&Y[rt + h * 768 + t * 4]) = ot;
    *(uint2*)(&Y[ri + h * 768 + t * 4]) = oi;
  }
}

// ---------------------------------------------------------------------------
// Grouped v-GEMM: G[4096][768] = Y_h * Wv_h^T + sat*bv (per head h).
__global__ __launch_bounds__(256, 4) void k_gemm_v(
    const u16* __restrict__ Yb,    // [4096,3072] bf16
    const u16* __restrict__ Wbf,   // [2304,768] bf16 (rows 1536+ = Wv)
    const float* __restrict__ bqkv,
    const float* __restrict__ sat, // [4096,4]
    u16* __restrict__ G)           // [4096,768] bf16
{
  __shared__ u16 sm[24576];
  int t = threadIdx.x;
  int lane = t & 63, wid = t >> 6;
  int wr = wid >> 1, wc = wid & 1;
  int lr = lane & 15, g4 = lane >> 4;
  int bm = blockIdx.x / 12, nt = blockIdx.x % 12;
  int h = nt / 3, e0 = (nt % 3) * 64;
  const size_t arow0 = (size_t)bm * 128;

  const u16* srcA[4];
  int dA[4];
#pragma unroll
  for (int j = 0; j < 4; ++j) {
    int c = j * 256 + t;
    int row = c >> 3, kg = (c & 7) ^ (row & 7);
    srcA[j] = Yb + (arow0 + row) * 3072 + h * 768 + kg * 8;
    dA[j] = c * 8;
  }
  const u16* srcB[2];
  int dB[2];
#pragma unroll
  for (int j = 0; j < 2; ++j) {
    int c = j * 256 + t;
    int row = c >> 3, kg = (c & 7) ^ (row & 7);
    srcB[j] = Wbf + (size_t)(1536 + h * DH_ + e0 + row) * 768 + kg * 8;
    dB[j] = c * 8;
  }

#define VSTAGE(abuf, bbuf, ktu) do { \
  gload16(srcA[0] + (ktu), &sm[(abuf) + dA[0]]); \
  gload16(srcA[1] + (ktu), &sm[(abuf) + dA[1]]); \
  gload16(srcA[2] + (ktu), &sm[(abuf) + dA[2]]); \
  gload16(srcA[3] + (ktu), &sm[(abuf) + dA[3]]); \
  gload16(srcB[0] + (ktu), &sm[(bbuf) + dB[0]]); \
  gload16(srcB[1] + (ktu), &sm[(bbuf) + dB[1]]); \
} while (0)

  int gx0 = g4 ^ (lr & 7);
  int aro = (wr * 64 + lr) * 64;
  int bro = (wc * 32 + lr) * 64;

  f32x4 acc[4][2] = {};

  VSTAGE(0, 16384, 0);
  asm volatile("s_waitcnt vmcnt(0)" ::: "memory");
  PHASE_BAR();

  for (int T = 0; T < NKT; ++T) {
    int abuf = (T & 1) * 8192, bbuf = 16384 + (T & 1) * 4096;
    bool pf = (T < NKT - 1);
    if (pf) VSTAGE(8192 - abuf, 20480 - (T & 1) * 4096, (T + 1) * 64);
#pragma unroll
    for (int kk = 0; kk < 2; ++kk) {
      int gx = gx0 ^ (kk * 4);
      bf16x8 a[4], bfr[2];
#pragma unroll
      for (int mi = 0; mi < 4; ++mi) a[mi] = *(const bf16x8*)(&sm[abuf + aro + mi * 1024 + gx * 8]);
#pragma unroll
      for (int ni = 0; ni < 2; ++ni) bfr[ni] = *(const bf16x8*)(&sm[bbuf + bro + ni * 1024 + gx * 8]);
#pragma unroll
      for (int mi = 0; mi < 4; ++mi)
#pragma unroll
        for (int ni = 0; ni < 2; ++ni)
          acc[mi][ni] = __builtin_amdgcn_mfma_f32_16x16x32_bf16(a[mi], bfr[ni], acc[mi][ni], 0, 0, 0);
    }
    if (pf) {
      asm volatile("s_waitcnt vmcnt(0)" ::: "memory");
      PHASE_BAR();
    }
  }

#pragma unroll
  for (int mi = 0; mi < 4; ++mi) {
#pragma unroll
    for (int ni = 0; ni < 2; ++ni) {
      int e = e0 + wc * 32 + ni * 16 + lr;
      int gcol = h * DH_ + e;
      float bv = bqkv[1536 + gcol];
#pragma unroll
      for (int i = 0; i < 4; ++i) {
        size_t row = arow0 + wr * 64 + mi * 16 + g4 * 4 + i;
        G[row * 768 + gcol] = f2bf(acc[mi][ni][i] + sat[row * 4 + h] * bv);
      }
    }
  }
#undef VSTAGE
}

// ---------------------------------------------------------------------------
// Head GEMM (unchanged, verified): F = tanh(G * w_out^T + b_out)
__global__ __launch_bounds__(512, 4) void k_gemm_head(
    const u16* __restrict__ Gb,   // [4096,768] bf16
    const u16* __restrict__ Wo,   // [768,768] bf16 (n-major)
    const float* __restrict__ bout,
    u16* __restrict__ F)          // [4096,768] bf16
{
  __shared__ u16 sm[32768];
  int t = threadIdx.x;
  int lane = t & 63, wid = t >> 6;
  int wr = wid >> 2, wc = wid & 3;
  int lr = lane & 15;
  int g4 = lane >> 4;

  int bm = blockIdx.x / 3, bn = blockIdx.x % 3;
  const size_t arow0 = (size_t)bm * 128;
  const int bcol0 = bn * 256;

  const u16* srcA[2];
  int dA[2];
#pragma unroll
  for (int j = 0; j < 2; ++j) {
    int c = j * 512 + t;
    srcA[j] = Gb + (arow0 + (c >> 3)) * 768 + ((c & 7) ^ ((c >> 3) & 7)) * 8;
    dA[j] = c * 8;
  }
  const u16* srcB[4];
  int dB[4];
#pragma unroll
  for (int j = 0; j < 4; ++j) {
    int c = j * 512 + t;
    srcB[j] = Wo + (size_t)(bcol0 + (c >> 3)) * 768 + ((c & 7) ^ ((c >> 3) & 7)) * 8;
    dB[j] = 16384 + c * 8;
  }

#define STAGE_A2(abuf, ktu) do { \
  gload16(srcA[0] + (ktu), &sm[(abuf) + dA[0]]); \
  gload16(srcA[1] + (ktu), &sm[(abuf) + dA[1]]); \
} while (0)
#define STAGE_B2(ktu) do { \
  gload16(srcB[0] + (ktu), &sm[dB[0]]); \
  gload16(srcB[1] + (ktu), &sm[dB[1]]); \
  gload16(srcB[2] + (ktu), &sm[dB[2]]); \
  gload16(srcB[3] + (ktu), &sm[dB[3]]); \
} while (0)

  int gx0 = g4 ^ (lr & 7);
  int aro = (wr * 64 + lr) * 64;
  int bro = 16384 + (wc * 64 + lr) * 64;

  f32x4 acc[4][4] = {};

  STAGE_A2(0, 0); STAGE_B2(0);
  asm volatile("s_waitcnt vmcnt(0)" ::: "memory");
  PHASE_BAR();

  int curA = 0;
  for (int T = 0; T < NKT; ++T) {
    int nxtA = 8192 - curA;
    bool pf = (T < NKT - 1);
    int ktu = (T + 1) * 64;
    bf16x8 bfr[4][2];
#pragma unroll
    for (int ni = 0; ni < 4; ++ni) {
      bfr[ni][0] = *(const bf16x8*)(&sm[bro + ni * 1024 + gx0 * 8]);
      bfr[ni][1] = *(const bf16x8*)(&sm[bro + ni * 1024 + (gx0 ^ 4) * 8]);
    }
    LGKM0();
    PHASE_BAR();
    if (pf) { STAGE_B2(ktu); STAGE_A2(nxtA, ktu); }
    __builtin_amdgcn_s_setprio(1);
#pragma unroll
    for (int kk = 0; kk < 2; ++kk) {
      int gx = gx0 ^ (kk * 4);
      bf16x8 afr[4];
#pragma unroll
      for (int mi = 0; mi < 4; ++mi)
        afr[mi] = *(const bf16x8*)(&sm[curA + aro + mi * 1024 + gx * 8]);
#pragma unroll
      for (int mi = 0; mi < 4; ++mi)
#pragma unroll
        for (int ni = 0; ni < 4; ++ni)
          acc[mi][ni] = __builtin_amdgcn_mfma_f32_16x16x32_bf16(afr[mi], bfr[ni][kk], acc[mi][ni], 0, 0, 0);
    }
    __builtin_amdgcn_s_setprio(0);
    if (pf) {
      asm volatile("s_waitcnt vmcnt(0)" ::: "memory");
      PHASE_BAR();
    }
    curA = nxtA;
  }

#pragma unroll
  for (int mi = 0; mi < 4; ++mi) {
#pragma unroll
    for (int ni = 0; ni < 4; ++ni) {
      int col = bcol0 + wc * 64 + ni * 16 + lr;
      float bb = bout[col];
#pragma unroll
      for (int i = 0; i < 4; ++i) {
        size_t row = arow0 + wr * 64 + mi * 16 + g4 * 4 + i;
        F[row * 768 + col] = f2bf(tanhf(acc[mi][ni][i] + bb));
      }
    }
  }
#undef STAGE_A2
#undef STAGE_B2
}

// ---------------------------------------------------------------------------
#define GC 4
__global__ __launch_bounds__(256) void k_cos(
    const u16* __restrict__ F,    // [4096,768] bf16 (tanh applied)
    float* __restrict__ out)      // [B_]
{
  __shared__ float red[3][4];
  int t = threadIdx.x, b0 = blockIdx.x * GC;
  int lane = t & 63, wid = t >> 6;
  for (int g = 0; g < GC; ++g) {
    int b = b0 + g;
    float st = 0, si = 0, sd = 0;
#pragma unroll
    for (int j = 0; j < 3; ++j) {
      int c = t + j * 256;
      float rt = bf2f(F[(size_t)b * 768 + c]);
      float ri = bf2f(F[(size_t)(2048 + b) * 768 + c]);
      st += rt * rt; si += ri * ri; sd += rt * ri;
    }
#pragma unroll
    for (int off = 32; off >= 1; off >>= 1) {
      st += __shfl_down(st, off);
      si += __shfl_down(si, off);
      sd += __shfl_down(sd, off);
    }
    __syncthreads();
    if (lane == 0) { red[0][wid] = st; red[1][wid] = si; red[2][wid] = sd; }
    __syncthreads();
    if (t == 0) {
      float S1 = red[0][0] + red[0][1] + red[0][2] + red[0][3];
      float S2 = red[1][0] + red[1][1] + red[1][2] + red[1][3];
      float S3 = red[2][0] + red[2][1] + red[2][2] + red[2][3];
      out[b] = S3 / (fmaxf(sqrtf(S1), 1e-8f) * fmaxf(sqrtf(S2), 1e-8f));
    }
  }
}

// ---------------------------------------------------------------------------
extern "C" void kernel_launch(void* const* d_in, const int* in_sizes, int n_in,
                              void* d_out, int out_size, void* d_ws, size_t ws_size,
                              hipStream_t stream) {
  const float* features = (const float*)d_in[0];
  // d_in[1] = attention_mask (unused by forward)
  const float* w_qkv = (const float*)d_in[2];
  const float* b_qkv = (const float*)d_in[3];
  const float* w_out = (const float*)d_in[4];
  const float* b_out = (const float*)d_in[5];
  float* out = (float*)d_out;

  char* ws = (char*)d_ws;
  size_t off = 0;
  auto alloc = [&](size_t bytes) {
    void* p = ws + off;
    off += (bytes + 255) & ~(size_t)255;
    return p;
  };
  u16* QK   = (u16*)alloc((size_t)M_ * TD2 * 2);     // 436 MB
  u16* Wbf  = (u16*)alloc((size_t)2304 * D_ * 2);    // 3.5 MB
  u16* Wobf = (u16*)alloc((size_t)D_ * D_ * 2);      // 1.2 MB
  u16* Yv   = (u16*)alloc((size_t)4096 * 3072 * 2);  // 25 MB
  float* AT = (float*)alloc((size_t)B_ * 4 * SP * 4); // 2.4 MB
  float* AI = (float*)alloc((size_t)B_ * 4 * SP * 4); // 2.4 MB
  float* sat = (float*)alloc((size_t)4096 * 4 * 4);  // 64 KB
  u16* G    = (u16*)alloc((size_t)4096 * D_ * 2);    // 6.3 MB
  u16* F    = (u16*)alloc((size_t)4096 * D_ * 2);    // 6.3 MB
  (void)ws_size;

  hipLaunchKernelGGL(k_cvt_bf16, dim3((2304 * D_ / 8 + 255) / 256), dim3(256), 0, stream,
                     w_qkv, Wbf, 2304 * D_ / 8);
  hipLaunchKernelGGL(k_cvt_bf16, dim3((D_ * D_ / 8 + 255) / 256), dim3(256), 0, stream,
                     w_out, Wobf, D_ * D_ / 8);

  hipLaunchKernelGGL(k_gemm_qkv, dim3(6 * 1136), dim3(512), 0, stream,
                     features, Wbf, b_qkv, QK);
  hipLaunchKernelGGL(k_attn_qk, dim3(B_ * H_), dim3(256), 0, stream, QK, AT, AI, sat);
  hipLaunchKernelGGL(k_accy, dim3(B_), dim3(192), 0, stream, features, AT, AI, Yv);
  hipLaunchKernelGGL(k_gemm_v, dim3(32 * 12), dim3(256), 0, stream,
                     Yv, Wbf, b_qkv, sat, G);
  hipLaunchKernelGGL(k_gemm_head, dim3(32 * 3), dim3(512), 0, stream,
                     G, Wobf, b_out, F);
  hipLaunchKernelGGL(k_cos, dim3(B_ / GC), dim3(256), 0, stream, F, out);
}

// Round 17
// 772.174 us; speedup vs baseline: 1.7180x; 1.0406x over previous
//
#include <hip/hip_runtime.h>
#include <hip/hip_bf16.h>

#define B_ 2048
#define S_ 71
#define SP 72               // padded stride for at/ai
#define D_ 768
#define H_ 4
#define DH_ 192
#define TD2 1536            // q,k only
#define M_ (B_ * S_)        // 145408 = 1136*128
#define TEXT_ 35
#define NKT 12              // 768 / 64 K-tiles

typedef unsigned short u16;
typedef unsigned int u32;
typedef __attribute__((ext_vector_type(4))) float f32x4;
typedef __attribute__((ext_vector_type(8))) short bf16x8;

__device__ __forceinline__ u16 f2bf(float f) {
  u32 u = __float_as_uint(f);
  u32 r = (u + 0x7FFFu + ((u >> 16) & 1u)) >> 16;  // RNE
  return (u16)r;
}
__device__ __forceinline__ float bf2f(u16 x) {
  return __uint_as_float(((u32)x) << 16);
}
__device__ __forceinline__ u32 pk2bf(float lo, float hi) {
  __hip_bfloat162 h = __float22bfloat162_rn(float2{lo, hi});
  return *reinterpret_cast<u32*>(&h);
}

typedef __attribute__((address_space(1))) const unsigned int GASU;
typedef __attribute__((address_space(3))) unsigned int LASU;
__device__ __forceinline__ void gload16(const void* g, void* l) {
  __builtin_amdgcn_global_load_lds((GASU*)g, (LASU*)l, 16, 0, 0);
}

#define PHASE_BAR() do { __builtin_amdgcn_s_barrier(); asm volatile("" ::: "memory"); } while (0)
#define LGKM0() do { asm volatile("s_waitcnt lgkmcnt(0)" ::: "memory"); __builtin_amdgcn_sched_barrier(0); } while (0)

// ---------------------------------------------------------------------------
__global__ __launch_bounds__(256) void k_cvt_bf16(const float* __restrict__ in,
                                                  u16* __restrict__ out, int n8) {
  int idx = blockIdx.x * 256 + threadIdx.x;
  if (idx >= n8) return;
  const float4* p = (const float4*)(in + (size_t)idx * 8);
  float4 a = p[0], b = p[1];
  uint4 o;
  o.x = pk2bf(a.x, a.y);
  o.y = pk2bf(a.z, a.w);
  o.z = pk2bf(b.x, b.y);
  o.w = pk2bf(b.z, b.w);
  *(uint4*)(out + (size_t)idx * 8) = o;
}

// ---------------------------------------------------------------------------
// Main GEMM — q,k only: C[M,1536] = phi(A(fp32) * Wqk^T + bias).
// 128x256, BK=64, A reg-staged dbuf, B gload_lds, 64KB LDS, 2 blocks/CU.
__global__ __launch_bounds__(512, 4) void k_gemm_qkv(
    const float* __restrict__ Afp,  // [M_,768] fp32 (features)
    const u16* __restrict__ Bw,     // [2304,768] bf16 (rows 0..1535 used)
    const float* __restrict__ bias, // [2304]
    u16* __restrict__ C)            // [M_,1536] bf16, phi everywhere
{
  __shared__ u16 sm[32768];   // 64 KiB
  int t = threadIdx.x;
  int lane = t & 63, wid = t >> 6;
  int wr = wid >> 2, wc = wid & 3;
  int lr = lane & 15;
  int g4 = lane >> 4;

  // XCD-bijective swizzle: nwg = 6816 = 8*852
  int swz = (blockIdx.x & 7) * 852 + (blockIdx.x >> 3);
  int bm = swz / 6, bn = swz % 6;
  const size_t arow0 = (size_t)bm * 128;
  const int bcol0 = bn * 256;

  const float* srcAf[2];
  int dA[2];
#pragma unroll
  for (int j = 0; j < 2; ++j) {
    int c = j * 512 + t;
    srcAf[j] = Afp + (arow0 + (c >> 3)) * 768 + ((c & 7) ^ ((c >> 3) & 7)) * 8;
    dA[j] = c * 8;
  }
  const u16* srcB[4];
  int dB[4];
#pragma unroll
  for (int j = 0; j < 4; ++j) {
    int c = j * 512 + t;
    srcB[j] = Bw + (size_t)(bcol0 + (c >> 3)) * 768 + ((c & 7) ^ ((c >> 3) & 7)) * 8;
    dB[j] = 16384 + c * 8;
  }

#define STAGE_B(ktu) do { \
  gload16(srcB[0] + (ktu), &sm[dB[0]]); \
  gload16(srcB[1] + (ktu), &sm[dB[1]]); \
  gload16(srcB[2] + (ktu), &sm[dB[2]]); \
  gload16(srcB[3] + (ktu), &sm[dB[3]]); \
} while (0)
#define LOADA(ktu) do { \
  fa0 = *(const float4*)(srcAf[0] + (ktu)); \
  fa1 = *(const float4*)(srcAf[0] + (ktu) + 4); \
  fa2 = *(const float4*)(srcAf[1] + (ktu)); \
  fa3 = *(const float4*)(srcAf[1] + (ktu) + 4); \
} while (0)
#define WRITEA(abuf) do { \
  uint4 o0; \
  o0.x = pk2bf(fa0.x, fa0.y); o0.y = pk2bf(fa0.z, fa0.w); \
  o0.z = pk2bf(fa1.x, fa1.y); o0.w = pk2bf(fa1.z, fa1.w); \
  *(uint4*)(&sm[(abuf) + dA[0]]) = o0; \
  uint4 o1; \
  o1.x = pk2bf(fa2.x, fa2.y); o1.y = pk2bf(fa2.z, fa2.w); \
  o1.z = pk2bf(fa3.x, fa3.y); o1.w = pk2bf(fa3.z, fa3.w); \
  *(uint4*)(&sm[(abuf) + dA[1]]) = o1; \
} while (0)

  int gx0 = g4 ^ (lr & 7);
  int aro = (wr * 64 + lr) * 64;
  int bro = 16384 + (wc * 64 + lr) * 64;

  f32x4 acc[4][4] = {};
  float4 fa0, fa1, fa2, fa3;

  LOADA(0);
  STAGE_B(0);
  asm volatile("s_waitcnt vmcnt(0)" ::: "memory");
  WRITEA(0);
  asm volatile("s_waitcnt lgkmcnt(0)" ::: "memory");
  PHASE_BAR();

  int curA = 0;
  for (int T = 0; T < NKT; ++T) {
    int nxtA = 8192 - curA;
    bool pf = (T < NKT - 1);
    int ktu = (T + 1) * 64;
    bf16x8 b0[4], a0[4];
#pragma unroll
    for (int ni = 0; ni < 4; ++ni) b0[ni] = *(const bf16x8*)(&sm[bro + ni * 1024 + gx0 * 8]);
#pragma unroll
    for (int mi = 0; mi < 4; ++mi) a0[mi] = *(const bf16x8*)(&sm[curA + aro + mi * 1024 + gx0 * 8]);
    __builtin_amdgcn_s_setprio(1);
#pragma unroll
    for (int mi = 0; mi < 4; ++mi)
#pragma unroll
      for (int ni = 0; ni < 4; ++ni)
        acc[mi][ni] = __builtin_amdgcn_mfma_f32_16x16x32_bf16(a0[mi], b0[ni], acc[mi][ni], 0, 0, 0);
    __builtin_amdgcn_s_setprio(0);
    int gx1 = gx0 ^ 4;
    bf16x8 b1[4];
#pragma unroll
    for (int ni = 0; ni < 4; ++ni) b1[ni] = *(const bf16x8*)(&sm[bro + ni * 1024 + gx1 * 8]);
    LGKM0();
    PHASE_BAR();
    if (pf) { STAGE_B(ktu); LOADA(ktu); }
    bf16x8 a1[4];
#pragma unroll
    for (int mi = 0; mi < 4; ++mi) a1[mi] = *(const bf16x8*)(&sm[curA + aro + mi * 1024 + gx1 * 8]);
    __builtin_amdgcn_s_setprio(1);
#pragma unroll
    for (int mi = 0; mi < 4; ++mi)
#pragma unroll
      for (int ni = 0; ni < 4; ++ni)
        acc[mi][ni] = __builtin_amdgcn_mfma_f32_16x16x32_bf16(a1[mi], b1[ni], acc[mi][ni], 0, 0, 0);
    __builtin_amdgcn_s_setprio(0);
    if (pf) {
      asm volatile("s_waitcnt vmcnt(0)" ::: "memory");
      WRITEA(nxtA);
      asm volatile("s_waitcnt lgkmcnt(0)" ::: "memory");
      PHASE_BAR();
    }
    curA = nxtA;
  }

#pragma unroll
  for (int mi = 0; mi < 4; ++mi) {
#pragma unroll
    for (int ni = 0; ni < 4; ++ni) {
      int col = bcol0 + wc * 64 + ni * 16 + lr;
      float bb = bias[col];
#pragma unroll
      for (int i = 0; i < 4; ++i) {
        size_t row = arow0 + wr * 64 + mi * 16 + g4 * 4 + i;
        float v = acc[mi][ni][i] + bb;
        v = (v > 0.0f) ? (v + 1.0f) : __expf(v);   // phi (q,k)
        C[row * TD2 + col] = f2bf(v);
      }
    }
  }
#undef STAGE_B
#undef LOADA
#undef WRITEA
}

// ---------------------------------------------------------------------------
// Attention qk-phases v2: one block per (b,h). ALD=200 (400B rows: 16B-aligned
// staging, bank-shift 4/row). z and qt phases wave-parallelized (4 waves x
// ~18-s chunk, lane covers d={ln,ln+64,ln+128}, LDS partials + 4-way reduce)
// instead of 71/142-deep serial loops. den/at stay 16-lane-group parallel.
#define ALD 200

__global__ __launch_bounds__(256) void k_attn_qk(
    const u16* __restrict__ qk,   // [M_,1536] bf16 (phi applied)
    float* __restrict__ AT,       // [B_,4,SP]
    float* __restrict__ AI,       // [B_,4,SP]
    float* __restrict__ sat)      // [4096,4]
{
  __shared__ u16 qs[S_ * ALD];
  __shared__ u16 ks[S_ * ALD];
  __shared__ float z[DH_], qt[DH_], qi[DH_], wt[S_], wi[S_];
  __shared__ float zp[4][DH_];          // wave partials (z phase)
  __shared__ float qp[4][DH_], qip[4][DH_];  // wave partials (qt phase)
  __shared__ float at_l[S_ + 1], ai_l[S_ + 1];
  int t = threadIdx.x;
  int b = blockIdx.x >> 2, h = blockIdx.x & 3;
  size_t base = (size_t)b * S_ * TD2;
  int qoff = h * DH_, koff = 768 + h * DH_;
  int grp = t >> 4, gl = t & 15;
  int w = t >> 6, ln = t & 63;

  // stage q,k: 16B chunks (ALD=200 -> 400B rows, always 16B-aligned)
  for (int idx = t; idx < S_ * 24; idx += 256) {
    int s = idx / 24, c = (idx % 24) * 8;
    *(uint4*)(&qs[s * ALD + c]) = *(const uint4*)(&qk[base + (size_t)s * TD2 + qoff + c]);
    *(uint4*)(&ks[s * ALD + c]) = *(const uint4*)(&qk[base + (size_t)s * TD2 + koff + c]);
  }
  __syncthreads();
  // z[d] = sum_s k[s,d] — wave-parallel partials over s-chunks
  {
    int s0 = w * 18, s1 = (w == 3) ? S_ : (s0 + 18);
    float p0 = 0, p1 = 0, p2 = 0;
    for (int s = s0; s < s1; ++s) {
      p0 += bf2f(ks[s * ALD + ln]);
      p1 += bf2f(ks[s * ALD + ln + 64]);
      p2 += bf2f(ks[s * ALD + ln + 128]);
    }
    zp[w][ln] = p0; zp[w][ln + 64] = p1; zp[w][ln + 128] = p2;
  }
  __syncthreads();
  if (t < DH_) z[t] = (zp[0][t] + zp[1][t]) + (zp[2][t] + zp[3][t]);
  __syncthreads();
  // den[s] = q[s,:].z — 16-lane-group parallel
  for (int s = grp; s < S_; s += 16) {
    float a = 0;
    int d0 = gl * 12;
#pragma unroll
    for (int i = 0; i < 12; ++i) a += bf2f(qs[s * ALD + d0 + i]) * z[d0 + i];
#pragma unroll
    for (int o = 8; o >= 1; o >>= 1) a += __shfl_xor(a, o);
    if (gl == 0) {
      float den = a + 1e-6f;
      wt[s] = (s < TEXT_) ? 1.0f / (35.0f * den) : 0.0f;
      wi[s] = (s >= TEXT_) ? 1.0f / (36.0f * den) : 0.0f;
    }
  }
  __syncthreads();
  // qt[d], qi[d] = sum_s q[s,d]*w[s] — wave-parallel partials
  {
    int s0 = w * 18, s1 = (w == 3) ? S_ : (s0 + 18);
    float pt0 = 0, pt1 = 0, pt2 = 0, pi0 = 0, pi1 = 0, pi2 = 0;
    for (int s = s0; s < s1; ++s) {
      float wts = wt[s], wis = wi[s];
      float q0 = bf2f(qs[s * ALD + ln]);
      float q1 = bf2f(qs[s * ALD + ln + 64]);
      float q2 = bf2f(qs[s * ALD + ln + 128]);
      pt0 += q0 * wts; pt1 += q1 * wts; pt2 += q2 * wts;
      pi0 += q0 * wis; pi1 += q1 * wis; pi2 += q2 * wis;
    }
    qp[w][ln] = pt0; qp[w][ln + 64] = pt1; qp[w][ln + 128] = pt2;
    qip[w][ln] = pi0; qip[w][ln + 64] = pi1; qip[w][ln + 128] = pi2;
  }
  __syncthreads();
  if (t < DH_) {
    qt[t] = (qp[0][t] + qp[1][t]) + (qp[2][t] + qp[3][t]);
    qi[t] = (qip[0][t] + qip[1][t]) + (qip[2][t] + qip[3][t]);
  }
  __syncthreads();
  // at[s], ai[s] = k[s,:].qt/.qi — group parallel
  size_t arow = ((size_t)b * 4 + h) * SP;
  for (int s = grp; s < S_; s += 16) {
    float aT = 0, aI = 0;
    int d0 = gl * 12;
#pragma unroll
    for (int i = 0; i < 12; ++i) {
      float kv = bf2f(ks[s * ALD + d0 + i]);
      aT += kv * qt[d0 + i]; aI += kv * qi[d0 + i];
    }
#pragma unroll
    for (int o = 8; o >= 1; o >>= 1) { aT += __shfl_xor(aT, o); aI += __shfl_xor(aI, o); }
    if (gl == 0) {
      at_l[s] = aT; ai_l[s] = aI;
      AT[arow + s] = aT; AI[arow + s] = aI;
    }
  }
  __syncthreads();
  if (t < 64) {
    float vT = at_l[t] + ((t < 7) ? at_l[t + 64] : 0.0f);
    float vI = ai_l[t] + ((t < 7) ? ai_l[t + 64] : 0.0f);
#pragma unroll
    for (int o = 32; o >= 1; o >>= 1) { vT += __shfl_xor(vT, o); vI += __shfl_xor(vI, o); }
    if (t == 0) {
      sat[(size_t)b * 4 + h] = vT;
      sat[(size_t)(2048 + b) * 4 + h] = vI;
    }
  }
}

// ---------------------------------------------------------------------------
// Y accumulation: block per b, 192 threads; streams x once (float4),
// accumulates y_t/y_i for all 4 heads in registers. Pure-BW kernel.
__global__ __launch_bounds__(192) void k_accy(
    const float* __restrict__ x,  // [B_,71,768] fp32
    const float* __restrict__ AT, // [B_,4,SP]
    const float* __restrict__ AI,
    u16* __restrict__ Y)          // [4096,3072] bf16
{
  __shared__ float at_s[4][S_], ai_s[4][S_];
  int t = threadIdx.x, b = blockIdx.x;
  for (int i = t; i < 4 * S_; i += 192) {
    int h = i / S_, s = i % S_;
    at_s[h][s] = AT[((size_t)b * 4 + h) * SP + s];
    ai_s[h][s] = AI[((size_t)b * 4 + h) * SP + s];
  }
  __syncthreads();
  float4 yt[4] = {}, yi[4] = {};
  const float4* xb = (const float4*)(x + (size_t)b * S_ * 768);
  for (int s = 0; s < S_; ++s) {
    float4 xv = xb[s * 192 + t];
#pragma unroll
    for (int h = 0; h < 4; ++h) {
      float a = at_s[h][s], ai_ = ai_s[h][s];
      yt[h].x += a * xv.x; yt[h].y += a * xv.y; yt[h].z += a * xv.z; yt[h].w += a * xv.w;
      yi[h].x += ai_ * xv.x; yi[h].y += ai_ * xv.y; yi[h].z += ai_ * xv.z; yi[h].w += ai_ * xv.w;
    }
  }
  size_t rt = (size_t)b * 3072, ri = (size_t)(2048 + b) * 3072;
#pragma unroll
  for (int h = 0; h < 4; ++h) {
    uint2 ot, oi;
    ot.x = pk2bf(yt[h].x, yt[h].y); ot.y = pk2bf(yt[h].z, yt[h].w);
    oi.x = pk2bf(yi[h].x, yi[h].y); oi.y = pk2bf(yi[h].z, yi[h].w);
    *(uint2*)(&Y[rt + h * 768 + t * 4]) = ot;
    *(uint2*)(&Y[ri + h * 768 + t * 4]) = oi;
  }
}

// ---------------------------------------------------------------------------
// Grouped v-GEMM: G[4096][768] = Y_h * Wv_h^T + sat*bv (per head h).
__global__ __launch_bounds__(256, 4) void k_gemm_v(
    const u16* __restrict__ Yb,    // [4096,3072] bf16
    const u16* __restrict__ Wbf,   // [2304,768] bf16 (rows 1536+ = Wv)
    const float* __restrict__ bqkv,
    const float* __restrict__ sat, // [4096,4]
    u16* __restrict__ G)           // [4096,768] bf16
{
  __shared__ u16 sm[24576];
  int t = threadIdx.x;
  int lane = t & 63, wid = t >> 6;
  int wr = wid >> 1, wc = wid & 1;
  int lr = lane & 15, g4 = lane >> 4;
  int bm = blockIdx.x / 12, nt = blockIdx.x % 12;
  int h = nt / 3, e0 = (nt % 3) * 64;
  const size_t arow0 = (size_t)bm * 128;

  const u16* srcA[4];
  int dA[4];
#pragma unroll
  for (int j = 0; j < 4; ++j) {
    int c = j * 256 + t;
    int row = c >> 3, kg = (c & 7) ^ (row & 7);
    srcA[j] = Yb + (arow0 + row) * 3072 + h * 768 + kg * 8;
    dA[j] = c * 8;
  }
  const u16* srcB[2];
  int dB[2];
#pragma unroll
  for (int j = 0; j < 2; ++j) {
    int c = j * 256 + t;
    int row = c >> 3, kg = (c & 7) ^ (row & 7);
    srcB[j] = Wbf + (size_t)(1536 + h * DH_ + e0 + row) * 768 + kg * 8;
    dB[j] = c * 8;
  }

#define VSTAGE(abuf, bbuf, ktu) do { \
  gload16(srcA[0] + (ktu), &sm[(abuf) + dA[0]]); \
  gload16(srcA[1] + (ktu), &sm[(abuf) + dA[1]]); \
  gload16(srcA[2] + (ktu), &sm[(abuf) + dA[2]]); \
  gload16(srcA[3] + (ktu), &sm[(abuf) + dA[3]]); \
  gload16(srcB[0] + (ktu), &sm[(bbuf) + dB[0]]); \
  gload16(srcB[1] + (ktu), &sm[(bbuf) + dB[1]]); \
} while (0)

  int gx0 = g4 ^ (lr & 7);
  int aro = (wr * 64 + lr) * 64;
  int bro = (wc * 32 + lr) * 64;

  f32x4 acc[4][2] = {};

  VSTAGE(0, 16384, 0);
  asm volatile("s_waitcnt vmcnt(0)" ::: "memory");
  PHASE_BAR();

  for (int T = 0; T < NKT; ++T) {
    int abuf = (T & 1) * 8192, bbuf = 16384 + (T & 1) * 4096;
    bool pf = (T < NKT - 1);
    if (pf) VSTAGE(8192 - abuf, 20480 - (T & 1) * 4096, (T + 1) * 64);
#pragma unroll
    for (int kk = 0; kk < 2; ++kk) {
      int gx = gx0 ^ (kk * 4);
      bf16x8 a[4], bfr[2];
#pragma unroll
      for (int mi = 0; mi < 4; ++mi) a[mi] = *(const bf16x8*)(&sm[abuf + aro + mi * 1024 + gx * 8]);
#pragma unroll
      for (int ni = 0; ni < 2; ++ni) bfr[ni] = *(const bf16x8*)(&sm[bbuf + bro + ni * 1024 + gx * 8]);
#pragma unroll
      for (int mi = 0; mi < 4; ++mi)
#pragma unroll
        for (int ni = 0; ni < 2; ++ni)
          acc[mi][ni] = __builtin_amdgcn_mfma_f32_16x16x32_bf16(a[mi], bfr[ni], acc[mi][ni], 0, 0, 0);
    }
    if (pf) {
      asm volatile("s_waitcnt vmcnt(0)" ::: "memory");
      PHASE_BAR();
    }
  }

#pragma unroll
  for (int mi = 0; mi < 4; ++mi) {
#pragma unroll
    for (int ni = 0; ni < 2; ++ni) {
      int e = e0 + wc * 32 + ni * 16 + lr;
      int gcol = h * DH_ + e;
      float bv = bqkv[1536 + gcol];
#pragma unroll
      for (int i = 0; i < 4; ++i) {
        size_t row = arow0 + wr * 64 + mi * 16 + g4 * 4 + i;
        G[row * 768 + gcol] = f2bf(acc[mi][ni][i] + sat[row * 4 + h] * bv);
      }
    }
  }
#undef VSTAGE
}

// ---------------------------------------------------------------------------
// Head GEMM (unchanged, verified): F = tanh(G * w_out^T + b_out)
__global__ __launch_bounds__(512, 4) void k_gemm_head(
    const u16* __restrict__ Gb,   // [4096,768] bf16
    const u16* __restrict__ Wo,   // [768,768] bf16 (n-major)
    const float* __restrict__ bout,
    u16* __restrict__ F)          // [4096,768] bf16
{
  __shared__ u16 sm[32768];
  int t = threadIdx.x;
  int lane = t & 63, wid = t >> 6;
  int wr = wid >> 2, wc = wid & 3;
  int lr = lane & 15;
  int g4 = lane >> 4;

  int bm = blockIdx.x / 3, bn = blockIdx.x % 3;
  const size_t arow0 = (size_t)bm * 128;
  const int bcol0 = bn * 256;

  const u16* srcA[2];
  int dA[2];
#pragma unroll
  for (int j = 0; j < 2; ++j) {
    int c = j * 512 + t;
    srcA[j] = Gb + (arow0 + (c >> 3)) * 768 + ((c & 7) ^ ((c >> 3) & 7)) * 8;
    dA[j] = c * 8;
  }
  const u16* srcB[4];
  int dB[4];
#pragma unroll
  for (int j = 0; j < 4; ++j) {
    int c = j * 512 + t;
    srcB[j] = Wo + (size_t)(bcol0 + (c >> 3)) * 768 + ((c & 7) ^ ((c >> 3) & 7)) * 8;
    dB[j] = 16384 + c * 8;
  }

#define STAGE_A2(abuf, ktu) do { \
  gload16(srcA[0] + (ktu), &sm[(abuf) + dA[0]]); \
  gload16(srcA[1] + (ktu), &sm[(abuf) + dA[1]]); \
} while (0)
#define STAGE_B2(ktu) do { \
  gload16(srcB[0] + (ktu), &sm[dB[0]]); \
  gload16(srcB[1] + (ktu), &sm[dB[1]]); \
  gload16(srcB[2] + (ktu), &sm[dB[2]]); \
  gload16(srcB[3] + (ktu), &sm[dB[3]]); \
} while (0)

  int gx0 = g4 ^ (lr & 7);
  int aro = (wr * 64 + lr) * 64;
  int bro = 16384 + (wc * 64 + lr) * 64;

  f32x4 acc[4][4] = {};

  STAGE_A2(0, 0); STAGE_B2(0);
  asm volatile("s_waitcnt vmcnt(0)" ::: "memory");
  PHASE_BAR();

  int curA = 0;
  for (int T = 0; T < NKT; ++T) {
    int nxtA = 8192 - curA;
    bool pf = (T < NKT - 1);
    int ktu = (T + 1) * 64;
    bf16x8 bfr[4][2];
#pragma unroll
    for (int ni = 0; ni < 4; ++ni) {
      bfr[ni][0] = *(const bf16x8*)(&sm[bro + ni * 1024 + gx0 * 8]);
      bfr[ni][1] = *(const bf16x8*)(&sm[bro + ni * 1024 + (gx0 ^ 4) * 8]);
    }
    LGKM0();
    PHASE_BAR();
    if (pf) { STAGE_B2(ktu); STAGE_A2(nxtA, ktu); }
    __builtin_amdgcn_s_setprio(1);
#pragma unroll
    for (int kk = 0; kk < 2; ++kk) {
      int gx = gx0 ^ (kk * 4);
      bf16x8 afr[4];
#pragma unroll
      for (int mi = 0; mi < 4; ++mi)
        afr[mi] = *(const bf16x8*)(&sm[curA + aro + mi * 1024 + gx * 8]);
#pragma unroll
      for (int mi = 0; mi < 4; ++mi)
#pragma unroll
        for (int ni = 0; ni < 4; ++ni)
          acc[mi][ni] = __builtin_amdgcn_mfma_f32_16x16x32_bf16(afr[mi], bfr[ni][kk], acc[mi][ni], 0, 0, 0);
    }
    __builtin_amdgcn_s_setprio(0);
    if (pf) {
      asm volatile("s_waitcnt vmcnt(0)" ::: "memory");
      PHASE_BAR();
    }
    curA = nxtA;
  }

#pragma unroll
  for (int mi = 0; mi < 4; ++mi) {
#pragma unroll
    for (int ni = 0; ni < 4; ++ni) {
      int col = bcol0 + wc * 64 + ni * 16 + lr;
      float bb = bout[col];
#pragma unroll
      for (int i = 0; i < 4; ++i) {
        size_t row = arow0 + wr * 64 + mi * 16 + g4 * 4 + i;
        F[row * 768 + col] = f2bf(tanhf(acc[mi][ni][i] + bb));
      }
    }
  }
#undef STAGE_A2
#undef STAGE_B2
}

// ---------------------------------------------------------------------------
#define GC 4
__global__ __launch_bounds__(256) void k_cos(
    const u16* __restrict__ F,    // [4096,768] bf16 (tanh applied)
    float* __restrict__ out)      // [B_]
{
  __shared__ float red[3][4];
  int t = threadIdx.x, b0 = blockIdx.x * GC;
  int lane = t & 63, wid = t >> 6;
  for (int g = 0; g < GC; ++g) {
    int b = b0 + g;
    float st = 0, si = 0, sd = 0;
#pragma unroll
    for (int j = 0; j < 3; ++j) {
      int c = t + j * 256;
      float rt = bf2f(F[(size_t)b * 768 + c]);
      float ri = bf2f(F[(size_t)(2048 + b) * 768 + c]);
      st += rt * rt; si += ri * ri; sd += rt * ri;
    }
#pragma unroll
    for (int off = 32; off >= 1; off >>= 1) {
      st += __shfl_down(st, off);
      si += __shfl_down(si, off);
      sd += __shfl_down(sd, off);
    }
    __syncthreads();
    if (lane == 0) { red[0][wid] = st; red[1][wid] = si; red[2][wid] = sd; }
    __syncthreads();
    if (t == 0) {
      float S1 = red[0][0] + red[0][1] + red[0][2] + red[0][3];
      float S2 = red[1][0] + red[1][1] + red[1][2] + red[1][3];
      float S3 = red[2][0] + red[2][1] + red[2][2] + red[2][3];
      out[b] = S3 / (fmaxf(sqrtf(S1), 1e-8f) * fmaxf(sqrtf(S2), 1e-8f));
    }
  }
}

// ---------------------------------------------------------------------------
extern "C" void kernel_launch(void* const* d_in, const int* in_sizes, int n_in,
                              void* d_out, int out_size, void* d_ws, size_t ws_size,
                              hipStream_t stream) {
  const float* features = (const float*)d_in[0];
  // d_in[1] = attention_mask (unused by forward)
  const float* w_qkv = (const float*)d_in[2];
  const float* b_qkv = (const float*)d_in[3];
  const float* w_out = (const float*)d_in[4];
  const float* b_out = (const float*)d_in[5];
  float* out = (float*)d_out;

  char* ws = (char*)d_ws;
  size_t off = 0;
  auto alloc = [&](size_t bytes) {
    void* p = ws + off;
    off += (bytes + 255) & ~(size_t)255;
    return p;
  };
  u16* QK   = (u16*)alloc((size_t)M_ * TD2 * 2);     // 436 MB
  u16* Wbf  = (u16*)alloc((size_t)2304 * D_ * 2);    // 3.5 MB
  u16* Wobf = (u16*)alloc((size_t)D_ * D_ * 2);      // 1.2 MB
  u16* Yv   = (u16*)alloc((size_t)4096 * 3072 * 2);  // 25 MB
  float* AT = (float*)alloc((size_t)B_ * 4 * SP * 4); // 2.4 MB
  float* AI = (float*)alloc((size_t)B_ * 4 * SP * 4); // 2.4 MB
  float* sat = (float*)alloc((size_t)4096 * 4 * 4);  // 64 KB
  u16* G    = (u16*)alloc((size_t)4096 * D_ * 2);    // 6.3 MB
  u16* F    = (u16*)alloc((size_t)4096 * D_ * 2);    // 6.3 MB
  (void)ws_size;

  hipLaunchKernelGGL(k_cvt_bf16, dim3((2304 * D_ / 8 + 255) / 256), dim3(256), 0, stream,
                     w_qkv, Wbf, 2304 * D_ / 8);
  hipLaunchKernelGGL(k_cvt_bf16, dim3((D_ * D_ / 8 + 255) / 256), dim3(256), 0, stream,
                     w_out, Wobf, D_ * D_ / 8);

  hipLaunchKernelGGL(k_gemm_qkv, dim3(6 * 1136), dim3(512), 0, stream,
                     features, Wbf, b_qkv, QK);
  hipLaunchKernelGGL(k_attn_qk, dim3(B_ * H_), dim3(256), 0, stream, QK, AT, AI, sat);
  hipLaunchKernelGGL(k_accy, dim3(B_), dim3(192), 0, stream, features, AT, AI, Yv);
  hipLaunchKernelGGL(k_gemm_v, dim3(32 * 12), dim3(256), 0, stream,
                     Yv, Wbf, b_qkv, sat, G);
  hipLaunchKernelGGL(k_gemm_head, dim3(32 * 3), dim3(512), 0, stream,
                     G, Wobf, b_out, F);
  hipLaunchKernelGGL(k_cos, dim3(B_ / GC), dim3(256), 0, stream, F, out);
}